// Round 6
// baseline (917.944 us; speedup 1.0000x reference)
//
#include <hip/hip_runtime.h>

#define NN 50000
#define NE 800000
#define DIN 128
#define DH 200
#define DHP 256   // padded hidden
#define DO 64
#define NBUCK 782     // ceil(NN/64)
#define CAP 2048      // bucket capacity; lambda=1023, sigma=32 -> +32 sigma

typedef float f32x4 __attribute__((ext_vector_type(4)));
typedef short bf16x8 __attribute__((ext_vector_type(8)));
typedef short s16x4 __attribute__((ext_vector_type(4)));
typedef unsigned int uint;

__device__ __forceinline__ unsigned short f2bf(float f) {
  unsigned int b = __float_as_uint(f);
  b = (b + 0x7FFFu + ((b >> 16) & 1u)) >> 16;
  return (unsigned short)b;
}
__device__ __forceinline__ float bf2f(unsigned short u) {
  return __uint_as_float((unsigned int)u << 16);
}

// ---------------- x (fp32) -> xb (bf16), 8 floats/thread; also zero cnt ----
__global__ __launch_bounds__(256) void k_cvt(const float* __restrict__ x,
                                             uint* __restrict__ xb,
                                             int* __restrict__ cnt) {
  int i = blockIdx.x * 256 + threadIdx.x;  // 800000 threads
  if (i < NBUCK) cnt[i] = 0;
  f32x4 a = *reinterpret_cast<const f32x4*>(x + (size_t)i * 8);
  f32x4 b = *reinterpret_cast<const f32x4*>(x + (size_t)i * 8 + 4);
  uint4 o;
  o.x = (uint)f2bf(a[0]) | ((uint)f2bf(a[1]) << 16);
  o.y = (uint)f2bf(a[2]) | ((uint)f2bf(a[3]) << 16);
  o.z = (uint)f2bf(b[0]) | ((uint)f2bf(b[1]) << 16);
  o.w = (uint)f2bf(b[2]) | ((uint)f2bf(b[3]) << 16);
  *reinterpret_cast<uint4*>(xb + (size_t)i * 4) = o;
}

// ---------------- bucketed scatter: bucket = row>>6, 4 edges/thread --------
// record: {col | (row&63)<<16, fp32 val}
__global__ __launch_bounds__(256) void k_scatter(const int* __restrict__ row,
                                                 const int* __restrict__ col,
                                                 const float* __restrict__ val,
                                                 int* __restrict__ cnt,
                                                 uint2* __restrict__ ep) {
  int base = blockIdx.x * 1024 + threadIdx.x * 4;
  if (base + 3 < NE) {
    int4 r4 = *reinterpret_cast<const int4*>(row + base);
    int4 c4 = *reinterpret_cast<const int4*>(col + base);
    float4 v4 = *reinterpret_cast<const float4*>(val + base);
    int b0 = r4.x >> 6, b1 = r4.y >> 6, b2 = r4.z >> 6, b3 = r4.w >> 6;
    int p0 = atomicAdd(&cnt[b0], 1);
    int p1 = atomicAdd(&cnt[b1], 1);
    int p2 = atomicAdd(&cnt[b2], 1);
    int p3 = atomicAdd(&cnt[b3], 1);
    if (p0 < CAP) ep[(size_t)b0 * CAP + p0] =
        make_uint2((uint)c4.x | ((uint)(r4.x & 63) << 16), __float_as_uint(v4.x));
    if (p1 < CAP) ep[(size_t)b1 * CAP + p1] =
        make_uint2((uint)c4.y | ((uint)(r4.y & 63) << 16), __float_as_uint(v4.y));
    if (p2 < CAP) ep[(size_t)b2 * CAP + p2] =
        make_uint2((uint)c4.z | ((uint)(r4.z & 63) << 16), __float_as_uint(v4.z));
    if (p3 < CAP) ep[(size_t)b3 * CAP + p3] =
        make_uint2((uint)c4.w | ((uint)(r4.w & 63) << 16), __float_as_uint(v4.w));
  } else {
#pragma unroll
    for (int k = 0; k < 4; ++k) {
      int e = base + k;
      if (e < NE) {
        int r = row[e];
        int b = r >> 6;
        int p = atomicAdd(&cnt[b], 1);
        if (p < CAP) ep[(size_t)b * CAP + p] =
            make_uint2((uint)col[e] | ((uint)(r & 63) << 16), __float_as_uint(val[e]));
      }
    }
  }
}

// ---------------- bucketed SpMM: block per 64-row bucket -------------------
// LDS acc[64][128] fp32, init = x rows; wave processes one edge (64 lanes x 2
// feats) per step via ds_add_f32; writeout bf16.
__global__ __launch_bounds__(256) void k_spmm_bin(const uint* __restrict__ xbu,
                                                  const uint2* __restrict__ ep,
                                                  const int* __restrict__ cnt,
                                                  uint* __restrict__ hu) {
  __shared__ float acc[64][128];
  const int tid = threadIdx.x;
  const int bucket = blockIdx.x;
  const int r0 = bucket << 6;
#pragma unroll
  for (int i = 0; i < 16; ++i) {
    int idx = i * 256 + tid;
    int rr = idx >> 6, u = idx & 63;
    int gr = r0 + rr;
    uint a = (gr < NN) ? xbu[(size_t)gr * 64 + u] : 0u;
    acc[rr][2 * u] = bf2f((unsigned short)a);
    acc[rr][2 * u + 1] = bf2f((unsigned short)(a >> 16));
  }
  __syncthreads();

  int n = cnt[bucket];
  if (n > CAP) n = CAP;
  const int w = tid >> 6, lane = tid & 63;
  const uint2* eb = ep + (size_t)bucket * CAP;
  int j = w;
  for (; j + 12 < n; j += 16) {
    uint2 e0 = eb[j], e1 = eb[j + 4], e2 = eb[j + 8], e3 = eb[j + 12];
    uint a0 = xbu[(size_t)(e0.x & 0xFFFFu) * 64 + lane];
    uint a1 = xbu[(size_t)(e1.x & 0xFFFFu) * 64 + lane];
    uint a2 = xbu[(size_t)(e2.x & 0xFFFFu) * 64 + lane];
    uint a3 = xbu[(size_t)(e3.x & 0xFFFFu) * 64 + lane];
    float v0 = __uint_as_float(e0.y), v1 = __uint_as_float(e1.y);
    float v2 = __uint_as_float(e2.y), v3 = __uint_as_float(e3.y);
    int l0 = (e0.x >> 16) & 63, l1 = (e1.x >> 16) & 63;
    int l2 = (e2.x >> 16) & 63, l3 = (e3.x >> 16) & 63;
    atomicAdd(&acc[l0][2 * lane],     v0 * bf2f((unsigned short)a0));
    atomicAdd(&acc[l0][2 * lane + 1], v0 * bf2f((unsigned short)(a0 >> 16)));
    atomicAdd(&acc[l1][2 * lane],     v1 * bf2f((unsigned short)a1));
    atomicAdd(&acc[l1][2 * lane + 1], v1 * bf2f((unsigned short)(a1 >> 16)));
    atomicAdd(&acc[l2][2 * lane],     v2 * bf2f((unsigned short)a2));
    atomicAdd(&acc[l2][2 * lane + 1], v2 * bf2f((unsigned short)(a2 >> 16)));
    atomicAdd(&acc[l3][2 * lane],     v3 * bf2f((unsigned short)a3));
    atomicAdd(&acc[l3][2 * lane + 1], v3 * bf2f((unsigned short)(a3 >> 16)));
  }
  for (; j < n; j += 4) {
    uint2 e0 = eb[j];
    uint a0 = xbu[(size_t)(e0.x & 0xFFFFu) * 64 + lane];
    float v0 = __uint_as_float(e0.y);
    int l0 = (e0.x >> 16) & 63;
    atomicAdd(&acc[l0][2 * lane],     v0 * bf2f((unsigned short)a0));
    atomicAdd(&acc[l0][2 * lane + 1], v0 * bf2f((unsigned short)(a0 >> 16)));
  }
  __syncthreads();

#pragma unroll
  for (int i = 0; i < 16; ++i) {
    int idx = i * 256 + tid;
    int rr = idx >> 6, u = idx & 63;
    int gr = r0 + rr;
    if (gr < NN)
      hu[(size_t)gr * 64 + u] =
          (uint)f2bf(acc[rr][2 * u]) | ((uint)f2bf(acc[rr][2 * u + 1]) << 16);
  }
}

// ---------------- pack W1+W2 -> MFMA B-fragment order ----------------------
// frag (t n-tile, s k-step, lane, j): n=t*16+(l&15), k=s*32+(j&3)+((l>>4)<<2)+((j>>2)<<4)
__global__ __launch_bounds__(256) void k_pack(const float* __restrict__ W1,
                                              const float* __restrict__ W2,
                                              unsigned short* __restrict__ B1p,
                                              unsigned short* __restrict__ B2p) {
  int gidx = blockIdx.x * 256 + threadIdx.x;  // 6144 total
  if (gidx < 4096) {
    int idx = gidx;
    int lane = idx & 63;
    int s = (idx >> 6) & 3;
    int t = idx >> 8;
    int n = t * 16 + (lane & 15);
    unsigned short v[8];
#pragma unroll
    for (int j = 0; j < 8; ++j) {
      int k = s * 32 + (j & 3) + ((lane >> 4) << 2) + ((j >> 2) << 4);
      float f = (n < DH) ? W1[(size_t)k * DH + n] : 0.f;
      v[j] = f2bf(f);
    }
    *reinterpret_cast<uint4*>(B1p + (size_t)idx * 8) =
        *reinterpret_cast<const uint4*>(v);
  } else {
    int idx = gidx - 4096;
    int lane = idx & 63;
    int s = (idx >> 6) & 7;
    int t = idx >> 9;
    int n = t * 16 + (lane & 15);
    unsigned short v[8];
#pragma unroll
    for (int j = 0; j < 8; ++j) {
      int k = s * 32 + (j & 3) + ((lane >> 4) << 2) + ((j >> 2) << 4);
      float f = (k < DH) ? W2[(size_t)k * DO + n] : 0.f;
      v[j] = f2bf(f);
    }
    *reinterpret_cast<uint4*>(B2p + (size_t)idx * 8) =
        *reinterpret_cast<const uint4*>(v);
  }
}

// ---------------- fused MLP: out = (relu(h@W1+b1)) @ W2 + b2 ---------------
// Block = 64 rows. Stage 1: 4 waves (2M x 2N), wave tile 32x128, H2 -> LDS.
// Stage 2: wave w handles rows w*16..w*16+15, K=256 from LDS, N=64.
__global__ __launch_bounds__(256) void k_mlp(const unsigned short* __restrict__ h,
                                             const unsigned short* __restrict__ B1p,
                                             const float* __restrict__ b1,
                                             const unsigned short* __restrict__ B2p,
                                             const float* __restrict__ b2,
                                             float* __restrict__ out) {
  __shared__ unsigned short hs[64][DHP + 8];  // +8 bf16 pad: stride 528 B
  const int tid = threadIdx.x;
  const int w = tid >> 6, l = tid & 63;
  const int wm = w >> 1, wn = w & 1;
  const int g = l >> 4, r16 = l & 15;
  const int m0 = blockIdx.x * 64 + wm * 32;

  f32x4 acc[2][8];
#pragma unroll
  for (int a = 0; a < 2; ++a)
#pragma unroll
    for (int b = 0; b < 8; ++b)
#pragma unroll
      for (int c = 0; c < 4; ++c) acc[a][b][c] = 0.f;

  int arow[2];
#pragma unroll
  for (int mr = 0; mr < 2; ++mr) {
    int rr = m0 + mr * 16 + r16;
    arow[mr] = rr < NN ? rr : NN - 1;
  }

  for (int s = 0; s < 4; ++s) {
    bf16x8 af[2];
#pragma unroll
    for (int mr = 0; mr < 2; ++mr) {
      const unsigned short* p = h + (size_t)arow[mr] * DIN + s * 32 + g * 4;
      s16x4 lo4 = *reinterpret_cast<const s16x4*>(p);
      s16x4 hi4 = *reinterpret_cast<const s16x4*>(p + 16);
#pragma unroll
      for (int j = 0; j < 4; ++j) { af[mr][j] = lo4[j]; af[mr][4 + j] = hi4[j]; }
    }
#pragma unroll
    for (int nr = 0; nr < 8; ++nr) {
      int t = wn * 8 + nr;
      bf16x8 bf = *reinterpret_cast<const bf16x8*>(B1p + (size_t)((t * 4 + s) * 64 + l) * 8);
      acc[0][nr] = __builtin_amdgcn_mfma_f32_16x16x32_bf16(af[0], bf, acc[0][nr], 0, 0, 0);
      acc[1][nr] = __builtin_amdgcn_mfma_f32_16x16x32_bf16(af[1], bf, acc[1][nr], 0, 0, 0);
    }
  }
  // bias + relu -> LDS (bf16)
#pragma unroll
  for (int mr = 0; mr < 2; ++mr)
#pragma unroll
    for (int nr = 0; nr < 8; ++nr) {
      int n = wn * 128 + nr * 16 + r16;
      float bias = (n < DH) ? b1[n] : 0.f;
#pragma unroll
      for (int i = 0; i < 4; ++i) {
        int rl = wm * 32 + mr * 16 + g * 4 + i;
        float v = acc[mr][nr][i] + bias;
        v = v > 0.f ? v : 0.f;
        if (n >= DH) v = 0.f;
        hs[rl][n] = f2bf(v);
      }
    }
  __syncthreads();

  // stage 2: rows w*16 .. w*16+15
  f32x4 acc2[4];
#pragma unroll
  for (int b = 0; b < 4; ++b)
#pragma unroll
    for (int c = 0; c < 4; ++c) acc2[b][c] = 0.f;

  for (int s = 0; s < 8; ++s) {
    const unsigned short* p = &hs[w * 16 + r16][s * 32 + g * 4];
    s16x4 lo4 = *reinterpret_cast<const s16x4*>(p);
    s16x4 hi4 = *reinterpret_cast<const s16x4*>(p + 16);
    bf16x8 af;
#pragma unroll
    for (int j = 0; j < 4; ++j) { af[j] = lo4[j]; af[4 + j] = hi4[j]; }
#pragma unroll
    for (int nr = 0; nr < 4; ++nr) {
      bf16x8 bf = *reinterpret_cast<const bf16x8*>(B2p + (size_t)((nr * 8 + s) * 64 + l) * 8);
      acc2[nr] = __builtin_amdgcn_mfma_f32_16x16x32_bf16(af, bf, acc2[nr], 0, 0, 0);
    }
  }
#pragma unroll
  for (int nr = 0; nr < 4; ++nr) {
    int n = nr * 16 + r16;
    float bias = b2[n];
#pragma unroll
    for (int i = 0; i < 4; ++i) {
      int grow = blockIdx.x * 64 + w * 16 + g * 4 + i;
      if (grow < NN) out[(size_t)grow * DO + n] = acc2[nr][i] + bias;
    }
  }
}

extern "C" void kernel_launch(void* const* d_in, const int* in_sizes, int n_in,
                              void* d_out, int out_size, void* d_ws, size_t ws_size,
                              hipStream_t stream) {
  const float* x = (const float*)d_in[0];
  const int* erow = (const int*)d_in[1];
  const int* ecol = (const int*)d_in[2];
  const float* eval_ = (const float*)d_in[3];
  const float* W1 = (const float*)d_in[4];
  const float* b1 = (const float*)d_in[5];
  const float* W2 = (const float*)d_in[6];
  const float* b2 = (const float*)d_in[7];
  float* out = (float*)d_out;

  char* ws = (char*)d_ws;
  size_t o = 0;
  uint* xb = (uint*)(ws + o);          o += (size_t)NN * 64 * 4;   // x bf16, 12.8 MB
  uint* hu = (uint*)(ws + o);          o += (size_t)NN * 64 * 4;   // h bf16, 12.8 MB
  unsigned short* B1p = (unsigned short*)(ws + o); o += 32768 * 2; // 64 KB
  unsigned short* B2p = (unsigned short*)(ws + o); o += 16384 * 2; // 32 KB
  o = (o + 255) & ~(size_t)255;
  int* cnt = (int*)(ws + o);           o += 4096;
  uint2* ep = (uint2*)(ws + o);        // NBUCK*CAP*8 = 12.8 MB

  k_cvt<<<3125, 256, 0, stream>>>(x, xb, cnt);
  k_scatter<<<(NE + 1023) / 1024, 256, 0, stream>>>(erow, ecol, eval_, cnt, ep);
  k_pack<<<24, 256, 0, stream>>>(W1, W2, B1p, B2p);
  k_spmm_bin<<<NBUCK, 256, 0, stream>>>(xb, ep, cnt, hu);
  k_mlp<<<(NN + 63) / 64, 256, 0, stream>>>((const unsigned short*)hu, B1p, b1,
                                            B2p, b2, out);
}

// Round 7
// 271.133 us; speedup vs baseline: 3.3856x; 3.3856x over previous
//
#include <hip/hip_runtime.h>

#define NN 50000
#define NE 800000
#define DIN 128
#define DH 200
#define DHP 256   // padded hidden
#define DO 64
#define NBUCK 782     // ceil(NN/64)
#define CAP 2048      // bucket capacity; lambda=1023, sigma=32 -> +32 sigma

typedef float f32x4 __attribute__((ext_vector_type(4)));
typedef short bf16x8 __attribute__((ext_vector_type(8)));
typedef short s16x4 __attribute__((ext_vector_type(4)));
typedef unsigned int uint;

__device__ __forceinline__ unsigned short f2bf(float f) {
  unsigned int b = __float_as_uint(f);
  b = (b + 0x7FFFu + ((b >> 16) & 1u)) >> 16;
  return (unsigned short)b;
}
__device__ __forceinline__ float bf2f(unsigned short u) {
  return __uint_as_float((unsigned int)u << 16);
}

// ---------------- x (fp32) -> xb (bf16), 8 floats/thread; also zero cnt ----
__global__ __launch_bounds__(256) void k_cvt(const float* __restrict__ x,
                                             uint* __restrict__ xb,
                                             int* __restrict__ cnt) {
  int i = blockIdx.x * 256 + threadIdx.x;  // 800000 threads
  if (i < NBUCK) cnt[i] = 0;
  f32x4 a = *reinterpret_cast<const f32x4*>(x + (size_t)i * 8);
  f32x4 b = *reinterpret_cast<const f32x4*>(x + (size_t)i * 8 + 4);
  uint4 o;
  o.x = (uint)f2bf(a[0]) | ((uint)f2bf(a[1]) << 16);
  o.y = (uint)f2bf(a[2]) | ((uint)f2bf(a[3]) << 16);
  o.z = (uint)f2bf(b[0]) | ((uint)f2bf(b[1]) << 16);
  o.w = (uint)f2bf(b[2]) | ((uint)f2bf(b[3]) << 16);
  *reinterpret_cast<uint4*>(xb + (size_t)i * 4) = o;
}

// ---------------- bucketed scatter: bucket = row>>6, 4 edges/thread --------
// record: {col | (row&63)<<16, fp32 val}
__global__ __launch_bounds__(256) void k_scatter(const int* __restrict__ row,
                                                 const int* __restrict__ col,
                                                 const float* __restrict__ val,
                                                 int* __restrict__ cnt,
                                                 uint2* __restrict__ ep) {
  int base = blockIdx.x * 1024 + threadIdx.x * 4;
  if (base + 3 < NE) {
    int4 r4 = *reinterpret_cast<const int4*>(row + base);
    int4 c4 = *reinterpret_cast<const int4*>(col + base);
    float4 v4 = *reinterpret_cast<const float4*>(val + base);
    int b0 = r4.x >> 6, b1 = r4.y >> 6, b2 = r4.z >> 6, b3 = r4.w >> 6;
    int p0 = atomicAdd(&cnt[b0], 1);
    int p1 = atomicAdd(&cnt[b1], 1);
    int p2 = atomicAdd(&cnt[b2], 1);
    int p3 = atomicAdd(&cnt[b3], 1);
    if (p0 < CAP) ep[(size_t)b0 * CAP + p0] =
        make_uint2((uint)c4.x | ((uint)(r4.x & 63) << 16), __float_as_uint(v4.x));
    if (p1 < CAP) ep[(size_t)b1 * CAP + p1] =
        make_uint2((uint)c4.y | ((uint)(r4.y & 63) << 16), __float_as_uint(v4.y));
    if (p2 < CAP) ep[(size_t)b2 * CAP + p2] =
        make_uint2((uint)c4.z | ((uint)(r4.z & 63) << 16), __float_as_uint(v4.z));
    if (p3 < CAP) ep[(size_t)b3 * CAP + p3] =
        make_uint2((uint)c4.w | ((uint)(r4.w & 63) << 16), __float_as_uint(v4.w));
  } else {
#pragma unroll
    for (int k = 0; k < 4; ++k) {
      int e = base + k;
      if (e < NE) {
        int r = row[e];
        int b = r >> 6;
        int p = atomicAdd(&cnt[b], 1);
        if (p < CAP) ep[(size_t)b * CAP + p] =
            make_uint2((uint)col[e] | ((uint)(r & 63) << 16), __float_as_uint(val[e]));
      }
    }
  }
}

// ---------------- bucketed SpMM: counting-sort in LDS, then row gather -----
// Block = 1 bucket (64 rows), 512 threads (8 waves). No LDS atomics on the
// feature path; each wave owns 8 rows, fp32 register accumulation.
__global__ __launch_bounds__(512) void k_spmm_bucket(const uint* __restrict__ xbu,
                                                     const uint2* __restrict__ ep,
                                                     const int* __restrict__ cnt,
                                                     uint* __restrict__ hu) {
  __shared__ uint2 se[CAP];            // 16 KB row-sorted records
  __shared__ int deg[64], rbase[64], rpos[64];
  const int tid = threadIdx.x;
  const int bucket = blockIdx.x;
  const int r0 = bucket << 6;

  if (tid < 64) deg[tid] = 0;
  __syncthreads();

  int n = cnt[bucket];
  if (n > CAP) n = CAP;
  const uint2* eb = ep + (size_t)bucket * CAP;

  // pass 1: per-row counts
  for (int j = tid; j < n; j += 512) {
    uint2 e = eb[j];
    atomicAdd(&deg[(e.x >> 16) & 63], 1);
  }
  __syncthreads();

  // wave 0: exclusive scan of 64 degrees
  if (tid < 64) {
    int v = deg[tid];
    int incl = v;
#pragma unroll
    for (int d = 1; d < 64; d <<= 1) {
      int t = __shfl_up(incl, d, 64);
      if (tid >= d) incl += t;
    }
    rbase[tid] = incl - v;
    rpos[tid] = incl - v;
  }
  __syncthreads();

  // pass 2: scatter records into row-sorted LDS order
  for (int j = tid; j < n; j += 512) {
    uint2 e = eb[j];
    int lr = (e.x >> 16) & 63;
    int p = atomicAdd(&rpos[lr], 1);
    se[p] = make_uint2(e.x & 0xFFFFu, e.y);
  }
  __syncthreads();

  // gather: wave w owns rows w, w+8, ..., w+56; lane owns 2 features
  const int w = tid >> 6, lane = tid & 63;
  for (int rr = w; rr < 64; rr += 8) {
    int gr = r0 + rr;
    if (gr >= NN) continue;
    int s = rbase[rr];
    int en = s + deg[rr];
    float ax = 0.f, ay = 0.f;
    int j = s;
    for (; j + 3 < en; j += 4) {
      uint2 e0 = se[j], e1 = se[j + 1], e2 = se[j + 2], e3 = se[j + 3];
      uint a0 = xbu[(size_t)e0.x * 64 + lane];
      uint a1 = xbu[(size_t)e1.x * 64 + lane];
      uint a2 = xbu[(size_t)e2.x * 64 + lane];
      uint a3 = xbu[(size_t)e3.x * 64 + lane];
      float v0 = __uint_as_float(e0.y), v1 = __uint_as_float(e1.y);
      float v2 = __uint_as_float(e2.y), v3 = __uint_as_float(e3.y);
      ax += v0 * bf2f((unsigned short)a0) + v1 * bf2f((unsigned short)a1) +
            v2 * bf2f((unsigned short)a2) + v3 * bf2f((unsigned short)a3);
      ay += v0 * bf2f((unsigned short)(a0 >> 16)) + v1 * bf2f((unsigned short)(a1 >> 16)) +
            v2 * bf2f((unsigned short)(a2 >> 16)) + v3 * bf2f((unsigned short)(a3 >> 16));
    }
    for (; j < en; ++j) {
      uint2 e0 = se[j];
      uint a0 = xbu[(size_t)e0.x * 64 + lane];
      float v0 = __uint_as_float(e0.y);
      ax += v0 * bf2f((unsigned short)a0);
      ay += v0 * bf2f((unsigned short)(a0 >> 16));
    }
    uint xs = xbu[(size_t)gr * 64 + lane];
    ax += bf2f((unsigned short)xs);
    ay += bf2f((unsigned short)(xs >> 16));
    hu[(size_t)gr * 64 + lane] = (uint)f2bf(ax) | ((uint)f2bf(ay) << 16);
  }
}

// ---------------- pack W1+W2 -> MFMA B-fragment order ----------------------
// frag (t n-tile, s k-step, lane, j): n=t*16+(l&15), k=s*32+(j&3)+((l>>4)<<2)+((j>>2)<<4)
__global__ __launch_bounds__(256) void k_pack(const float* __restrict__ W1,
                                              const float* __restrict__ W2,
                                              unsigned short* __restrict__ B1p,
                                              unsigned short* __restrict__ B2p) {
  int gidx = blockIdx.x * 256 + threadIdx.x;  // 6144 total
  if (gidx < 4096) {
    int idx = gidx;
    int lane = idx & 63;
    int s = (idx >> 6) & 3;
    int t = idx >> 8;
    int n = t * 16 + (lane & 15);
    unsigned short v[8];
#pragma unroll
    for (int j = 0; j < 8; ++j) {
      int k = s * 32 + (j & 3) + ((lane >> 4) << 2) + ((j >> 2) << 4);
      float f = (n < DH) ? W1[(size_t)k * DH + n] : 0.f;
      v[j] = f2bf(f);
    }
    *reinterpret_cast<uint4*>(B1p + (size_t)idx * 8) =
        *reinterpret_cast<const uint4*>(v);
  } else {
    int idx = gidx - 4096;
    int lane = idx & 63;
    int s = (idx >> 6) & 7;
    int t = idx >> 9;
    int n = t * 16 + (lane & 15);
    unsigned short v[8];
#pragma unroll
    for (int j = 0; j < 8; ++j) {
      int k = s * 32 + (j & 3) + ((lane >> 4) << 2) + ((j >> 2) << 4);
      float f = (k < DH) ? W2[(size_t)k * DO + n] : 0.f;
      v[j] = f2bf(f);
    }
    *reinterpret_cast<uint4*>(B2p + (size_t)idx * 8) =
        *reinterpret_cast<const uint4*>(v);
  }
}

// ---------------- fused MLP: out = (relu(h@W1+b1)) @ W2 + b2 ---------------
// Block = 64 rows. Stage 1: 4 waves (2M x 2N), wave tile 32x128, H2 -> LDS.
// Stage 2: wave w handles rows w*16..w*16+15, K=256 from LDS, N=64.
__global__ __launch_bounds__(256) void k_mlp(const unsigned short* __restrict__ h,
                                             const unsigned short* __restrict__ B1p,
                                             const float* __restrict__ b1,
                                             const unsigned short* __restrict__ B2p,
                                             const float* __restrict__ b2,
                                             float* __restrict__ out) {
  __shared__ unsigned short hs[64][DHP + 8];  // +8 bf16 pad: stride 528 B
  const int tid = threadIdx.x;
  const int w = tid >> 6, l = tid & 63;
  const int wm = w >> 1, wn = w & 1;
  const int g = l >> 4, r16 = l & 15;
  const int m0 = blockIdx.x * 64 + wm * 32;

  f32x4 acc[2][8];
#pragma unroll
  for (int a = 0; a < 2; ++a)
#pragma unroll
    for (int b = 0; b < 8; ++b)
#pragma unroll
      for (int c = 0; c < 4; ++c) acc[a][b][c] = 0.f;

  int arow[2];
#pragma unroll
  for (int mr = 0; mr < 2; ++mr) {
    int rr = m0 + mr * 16 + r16;
    arow[mr] = rr < NN ? rr : NN - 1;
  }

  for (int s = 0; s < 4; ++s) {
    bf16x8 af[2];
#pragma unroll
    for (int mr = 0; mr < 2; ++mr) {
      const unsigned short* p = h + (size_t)arow[mr] * DIN + s * 32 + g * 4;
      s16x4 lo4 = *reinterpret_cast<const s16x4*>(p);
      s16x4 hi4 = *reinterpret_cast<const s16x4*>(p + 16);
#pragma unroll
      for (int j = 0; j < 4; ++j) { af[mr][j] = lo4[j]; af[mr][4 + j] = hi4[j]; }
    }
#pragma unroll
    for (int nr = 0; nr < 8; ++nr) {
      int t = wn * 8 + nr;
      bf16x8 bf = *reinterpret_cast<const bf16x8*>(B1p + (size_t)((t * 4 + s) * 64 + l) * 8);
      acc[0][nr] = __builtin_amdgcn_mfma_f32_16x16x32_bf16(af[0], bf, acc[0][nr], 0, 0, 0);
      acc[1][nr] = __builtin_amdgcn_mfma_f32_16x16x32_bf16(af[1], bf, acc[1][nr], 0, 0, 0);
    }
  }
  // bias + relu -> LDS (bf16)
#pragma unroll
  for (int mr = 0; mr < 2; ++mr)
#pragma unroll
    for (int nr = 0; nr < 8; ++nr) {
      int n = wn * 128 + nr * 16 + r16;
      float bias = (n < DH) ? b1[n] : 0.f;
#pragma unroll
      for (int i = 0; i < 4; ++i) {
        int rl = wm * 32 + mr * 16 + g * 4 + i;
        float v = acc[mr][nr][i] + bias;
        v = v > 0.f ? v : 0.f;
        if (n >= DH) v = 0.f;
        hs[rl][n] = f2bf(v);
      }
    }
  __syncthreads();

  // stage 2: rows w*16 .. w*16+15
  f32x4 acc2[4];
#pragma unroll
  for (int b = 0; b < 4; ++b)
#pragma unroll
    for (int c = 0; c < 4; ++c) acc2[b][c] = 0.f;

  for (int s = 0; s < 8; ++s) {
    const unsigned short* p = &hs[w * 16 + r16][s * 32 + g * 4];
    s16x4 lo4 = *reinterpret_cast<const s16x4*>(p);
    s16x4 hi4 = *reinterpret_cast<const s16x4*>(p + 16);
    bf16x8 af;
#pragma unroll
    for (int j = 0; j < 4; ++j) { af[j] = lo4[j]; af[4 + j] = hi4[j]; }
#pragma unroll
    for (int nr = 0; nr < 4; ++nr) {
      bf16x8 bf = *reinterpret_cast<const bf16x8*>(B2p + (size_t)((nr * 8 + s) * 64 + l) * 8);
      acc2[nr] = __builtin_amdgcn_mfma_f32_16x16x32_bf16(af, bf, acc2[nr], 0, 0, 0);
    }
  }
#pragma unroll
  for (int nr = 0; nr < 4; ++nr) {
    int n = nr * 16 + r16;
    float bias = b2[n];
#pragma unroll
    for (int i = 0; i < 4; ++i) {
      int grow = blockIdx.x * 64 + w * 16 + g * 4 + i;
      if (grow < NN) out[(size_t)grow * DO + n] = acc2[nr][i] + bias;
    }
  }
}

extern "C" void kernel_launch(void* const* d_in, const int* in_sizes, int n_in,
                              void* d_out, int out_size, void* d_ws, size_t ws_size,
                              hipStream_t stream) {
  const float* x = (const float*)d_in[0];
  const int* erow = (const int*)d_in[1];
  const int* ecol = (const int*)d_in[2];
  const float* eval_ = (const float*)d_in[3];
  const float* W1 = (const float*)d_in[4];
  const float* b1 = (const float*)d_in[5];
  const float* W2 = (const float*)d_in[6];
  const float* b2 = (const float*)d_in[7];
  float* out = (float*)d_out;

  char* ws = (char*)d_ws;
  size_t o = 0;
  uint* xb = (uint*)(ws + o);          o += (size_t)NN * 64 * 4;   // x bf16, 12.8 MB
  uint* hu = (uint*)(ws + o);          o += (size_t)NN * 64 * 4;   // h bf16, 12.8 MB
  unsigned short* B1p = (unsigned short*)(ws + o); o += 32768 * 2; // 64 KB
  unsigned short* B2p = (unsigned short*)(ws + o); o += 16384 * 2; // 32 KB
  o = (o + 255) & ~(size_t)255;
  int* cnt = (int*)(ws + o);           o += 4096;
  uint2* ep = (uint2*)(ws + o);        // NBUCK*CAP*8 = 12.8 MB

  k_cvt<<<3125, 256, 0, stream>>>(x, xb, cnt);
  k_scatter<<<(NE + 1023) / 1024, 256, 0, stream>>>(erow, ecol, eval_, cnt, ep);
  k_pack<<<24, 256, 0, stream>>>(W1, W2, B1p, B2p);
  k_spmm_bucket<<<NBUCK, 512, 0, stream>>>(xb, ep, cnt, hu);
  k_mlp<<<(NN + 63) / 64, 256, 0, stream>>>((const unsigned short*)hu, B1p, b1,
                                            B2p, b2, out);
}

// Round 8
// 102.949 us; speedup vs baseline: 8.9165x; 2.6337x over previous
//
#include <hip/hip_runtime.h>

#define NN 50000
#define NE 800000
#define DIN 128
#define DH 200
#define DHP 256   // padded hidden
#define DO 64
#define NBUCK 782     // ceil(NN/64)
#define CAP 2048      // bucket capacity; lambda=1023, sigma=32 -> +32 sigma
#define EPB 4096      // edges per histogram/scatter block
#define NBLK_E ((NE + EPB - 1) / EPB)   // 196

typedef float f32x4 __attribute__((ext_vector_type(4)));
typedef short bf16x8 __attribute__((ext_vector_type(8)));
typedef short s16x4 __attribute__((ext_vector_type(4)));
typedef unsigned int uint;

__device__ __forceinline__ unsigned short f2bf(float f) {
  unsigned int b = __float_as_uint(f);
  b = (b + 0x7FFFu + ((b >> 16) & 1u)) >> 16;
  return (unsigned short)b;
}
__device__ __forceinline__ float bf2f(unsigned short u) {
  return __uint_as_float((unsigned int)u << 16);
}

// ---------------- x (fp32) -> xb (bf16), 8 floats/thread -------------------
__global__ __launch_bounds__(256) void k_cvt(const float* __restrict__ x,
                                             uint* __restrict__ xb) {
  int i = blockIdx.x * 256 + threadIdx.x;  // 800000 threads
  f32x4 a = *reinterpret_cast<const f32x4*>(x + (size_t)i * 8);
  f32x4 b = *reinterpret_cast<const f32x4*>(x + (size_t)i * 8 + 4);
  uint4 o;
  o.x = (uint)f2bf(a[0]) | ((uint)f2bf(a[1]) << 16);
  o.y = (uint)f2bf(a[2]) | ((uint)f2bf(a[3]) << 16);
  o.z = (uint)f2bf(b[0]) | ((uint)f2bf(b[1]) << 16);
  o.w = (uint)f2bf(b[2]) | ((uint)f2bf(b[3]) << 16);
  *reinterpret_cast<uint4*>(xb + (size_t)i * 4) = o;
}

// ---------------- phase A: block-local bucket histogram --------------------
__global__ __launch_bounds__(256) void k_histA(const int* __restrict__ row,
                                               int* __restrict__ hist) {
  __shared__ int lh[NBUCK];
  const int tid = threadIdx.x;
  const int e0 = blockIdx.x * EPB;
  for (int j = tid; j < NBUCK; j += 256) lh[j] = 0;
  __syncthreads();
#pragma unroll
  for (int p = 0; p < EPB / 256; ++p) {
    int e = e0 + p * 256 + tid;
    if (e < NE) atomicAdd(&lh[row[e] >> 6], 1);
  }
  __syncthreads();
  int* hrow = hist + (size_t)blockIdx.x * NBUCK;
  for (int j = tid; j < NBUCK; j += 256) hrow[j] = lh[j];
}

// ---------------- phase B: per-bucket scan across blocks -------------------
// block k: excl-scan hist[0..NBLK_E)[k]; write back bases; cnt[k] = total
__global__ __launch_bounds__(256) void k_scanB(int* __restrict__ hist,
                                               int* __restrict__ cnt) {
  __shared__ int ws[4];
  const int k = blockIdx.x;
  const int tid = threadIdx.x;
  int v = (tid < NBLK_E) ? hist[(size_t)tid * NBUCK + k] : 0;
  int lane = tid & 63, wid = tid >> 6;
  int incl = v;
#pragma unroll
  for (int d = 1; d < 64; d <<= 1) {
    int t = __shfl_up(incl, d, 64);
    if (lane >= d) incl += t;
  }
  if (lane == 63) ws[wid] = incl;
  __syncthreads();
  if (tid == 0) {
    int s = 0;
#pragma unroll
    for (int q = 0; q < 4; ++q) { int xx = ws[q]; ws[q] = s; s += xx; }
  }
  __syncthreads();
  int excl = ws[wid] + incl - v;
  if (tid < NBLK_E) hist[(size_t)tid * NBUCK + k] = excl;
  if (tid == 255) cnt[k] = excl;  // v==0 here -> excl == total
}

// ---------------- phase C: rank + scatter (single-writer segments) ---------
__global__ __launch_bounds__(256) void k_scatC(const int* __restrict__ row,
                                               const int* __restrict__ col,
                                               const float* __restrict__ val,
                                               const int* __restrict__ hist,
                                               uint2* __restrict__ ep) {
  __shared__ int lh[NBUCK];
  __shared__ int lbase[NBUCK];
  const int tid = threadIdx.x;
  const int e0 = blockIdx.x * EPB;
  const int* hrow = hist + (size_t)blockIdx.x * NBUCK;
  for (int j = tid; j < NBUCK; j += 256) { lh[j] = 0; lbase[j] = hrow[j]; }
  __syncthreads();
#pragma unroll
  for (int p = 0; p < EPB / 256; ++p) {
    int e = e0 + p * 256 + tid;
    if (e < NE) {
      int r = row[e];
      int k = r >> 6;
      int rank = atomicAdd(&lh[k], 1);
      int pos = lbase[k] + rank;
      if (pos < CAP)
        ep[(size_t)k * CAP + pos] =
            make_uint2((uint)col[e] | ((uint)(r & 63) << 16), __float_as_uint(val[e]));
    }
  }
}

// ---------------- bucketed SpMM: counting-sort in LDS, then row gather -----
__global__ __launch_bounds__(512) void k_spmm_bucket(const uint* __restrict__ xbu,
                                                     const uint2* __restrict__ ep,
                                                     const int* __restrict__ cnt,
                                                     uint* __restrict__ hu) {
  __shared__ uint2 se[CAP];            // 16 KB row-sorted records
  __shared__ int deg[64], rbase[64], rpos[64];
  const int tid = threadIdx.x;
  const int bucket = blockIdx.x;
  const int r0 = bucket << 6;

  if (tid < 64) deg[tid] = 0;
  __syncthreads();

  int n = cnt[bucket];
  if (n > CAP) n = CAP;
  const uint2* eb = ep + (size_t)bucket * CAP;

  // pass 1: per-row counts
  for (int j = tid; j < n; j += 512) {
    uint2 e = eb[j];
    atomicAdd(&deg[(e.x >> 16) & 63], 1);
  }
  __syncthreads();

  // wave 0: exclusive scan of 64 degrees
  if (tid < 64) {
    int v = deg[tid];
    int incl = v;
#pragma unroll
    for (int d = 1; d < 64; d <<= 1) {
      int t = __shfl_up(incl, d, 64);
      if (tid >= d) incl += t;
    }
    rbase[tid] = incl - v;
    rpos[tid] = incl - v;
  }
  __syncthreads();

  // pass 2: scatter records into row-sorted LDS order
  for (int j = tid; j < n; j += 512) {
    uint2 e = eb[j];
    int lr = (e.x >> 16) & 63;
    int p = atomicAdd(&rpos[lr], 1);
    se[p] = make_uint2(e.x & 0xFFFFu, e.y);
  }
  __syncthreads();

  // gather: wave w owns rows w, w+8, ..., w+56; lane owns 2 features
  const int w = tid >> 6, lane = tid & 63;
  for (int rr = w; rr < 64; rr += 8) {
    int gr = r0 + rr;
    if (gr >= NN) continue;
    int s = rbase[rr];
    int en = s + deg[rr];
    float ax = 0.f, ay = 0.f;
    int j = s;
    for (; j + 3 < en; j += 4) {
      uint2 e0 = se[j], e1 = se[j + 1], e2 = se[j + 2], e3 = se[j + 3];
      uint a0 = xbu[(size_t)e0.x * 64 + lane];
      uint a1 = xbu[(size_t)e1.x * 64 + lane];
      uint a2 = xbu[(size_t)e2.x * 64 + lane];
      uint a3 = xbu[(size_t)e3.x * 64 + lane];
      float v0 = __uint_as_float(e0.y), v1 = __uint_as_float(e1.y);
      float v2 = __uint_as_float(e2.y), v3 = __uint_as_float(e3.y);
      ax += v0 * bf2f((unsigned short)a0) + v1 * bf2f((unsigned short)a1) +
            v2 * bf2f((unsigned short)a2) + v3 * bf2f((unsigned short)a3);
      ay += v0 * bf2f((unsigned short)(a0 >> 16)) + v1 * bf2f((unsigned short)(a1 >> 16)) +
            v2 * bf2f((unsigned short)(a2 >> 16)) + v3 * bf2f((unsigned short)(a3 >> 16));
    }
    for (; j < en; ++j) {
      uint2 e0 = se[j];
      uint a0 = xbu[(size_t)e0.x * 64 + lane];
      float v0 = __uint_as_float(e0.y);
      ax += v0 * bf2f((unsigned short)a0);
      ay += v0 * bf2f((unsigned short)(a0 >> 16));
    }
    uint xs = xbu[(size_t)gr * 64 + lane];
    ax += bf2f((unsigned short)xs);
    ay += bf2f((unsigned short)(xs >> 16));
    hu[(size_t)gr * 64 + lane] = (uint)f2bf(ax) | ((uint)f2bf(ay) << 16);
  }
}

// ---------------- pack W1+W2 -> MFMA B-fragment order ----------------------
__global__ __launch_bounds__(256) void k_pack(const float* __restrict__ W1,
                                              const float* __restrict__ W2,
                                              unsigned short* __restrict__ B1p,
                                              unsigned short* __restrict__ B2p) {
  int gidx = blockIdx.x * 256 + threadIdx.x;  // 6144 total
  if (gidx < 4096) {
    int idx = gidx;
    int lane = idx & 63;
    int s = (idx >> 6) & 3;
    int t = idx >> 8;
    int n = t * 16 + (lane & 15);
    unsigned short v[8];
#pragma unroll
    for (int j = 0; j < 8; ++j) {
      int k = s * 32 + (j & 3) + ((lane >> 4) << 2) + ((j >> 2) << 4);
      float f = (n < DH) ? W1[(size_t)k * DH + n] : 0.f;
      v[j] = f2bf(f);
    }
    *reinterpret_cast<uint4*>(B1p + (size_t)idx * 8) =
        *reinterpret_cast<const uint4*>(v);
  } else {
    int idx = gidx - 4096;
    int lane = idx & 63;
    int s = (idx >> 6) & 7;
    int t = idx >> 9;
    int n = t * 16 + (lane & 15);
    unsigned short v[8];
#pragma unroll
    for (int j = 0; j < 8; ++j) {
      int k = s * 32 + (j & 3) + ((lane >> 4) << 2) + ((j >> 2) << 4);
      float f = (k < DH) ? W2[(size_t)k * DO + n] : 0.f;
      v[j] = f2bf(f);
    }
    *reinterpret_cast<uint4*>(B2p + (size_t)idx * 8) =
        *reinterpret_cast<const uint4*>(v);
  }
}

// ---------------- fused MLP: out = (relu(h@W1+b1)) @ W2 + b2 ---------------
__global__ __launch_bounds__(256) void k_mlp(const unsigned short* __restrict__ h,
                                             const unsigned short* __restrict__ B1p,
                                             const float* __restrict__ b1,
                                             const unsigned short* __restrict__ B2p,
                                             const float* __restrict__ b2,
                                             float* __restrict__ out) {
  __shared__ unsigned short hs[64][DHP + 8];  // +8 bf16 pad: stride 528 B
  const int tid = threadIdx.x;
  const int w = tid >> 6, l = tid & 63;
  const int wm = w >> 1, wn = w & 1;
  const int g = l >> 4, r16 = l & 15;
  const int m0 = blockIdx.x * 64 + wm * 32;

  f32x4 acc[2][8];
#pragma unroll
  for (int a = 0; a < 2; ++a)
#pragma unroll
    for (int b = 0; b < 8; ++b)
#pragma unroll
      for (int c = 0; c < 4; ++c) acc[a][b][c] = 0.f;

  int arow[2];
#pragma unroll
  for (int mr = 0; mr < 2; ++mr) {
    int rr = m0 + mr * 16 + r16;
    arow[mr] = rr < NN ? rr : NN - 1;
  }

  for (int s = 0; s < 4; ++s) {
    bf16x8 af[2];
#pragma unroll
    for (int mr = 0; mr < 2; ++mr) {
      const unsigned short* p = h + (size_t)arow[mr] * DIN + s * 32 + g * 4;
      s16x4 lo4 = *reinterpret_cast<const s16x4*>(p);
      s16x4 hi4 = *reinterpret_cast<const s16x4*>(p + 16);
#pragma unroll
      for (int j = 0; j < 4; ++j) { af[mr][j] = lo4[j]; af[mr][4 + j] = hi4[j]; }
    }
#pragma unroll
    for (int nr = 0; nr < 8; ++nr) {
      int t = wn * 8 + nr;
      bf16x8 bf = *reinterpret_cast<const bf16x8*>(B1p + (size_t)((t * 4 + s) * 64 + l) * 8);
      acc[0][nr] = __builtin_amdgcn_mfma_f32_16x16x32_bf16(af[0], bf, acc[0][nr], 0, 0, 0);
      acc[1][nr] = __builtin_amdgcn_mfma_f32_16x16x32_bf16(af[1], bf, acc[1][nr], 0, 0, 0);
    }
  }
  // bias + relu -> LDS (bf16)
#pragma unroll
  for (int mr = 0; mr < 2; ++mr)
#pragma unroll
    for (int nr = 0; nr < 8; ++nr) {
      int n = wn * 128 + nr * 16 + r16;
      float bias = (n < DH) ? b1[n] : 0.f;
#pragma unroll
      for (int i = 0; i < 4; ++i) {
        int rl = wm * 32 + mr * 16 + g * 4 + i;
        float v = acc[mr][nr][i] + bias;
        v = v > 0.f ? v : 0.f;
        if (n >= DH) v = 0.f;
        hs[rl][n] = f2bf(v);
      }
    }
  __syncthreads();

  // stage 2: rows w*16 .. w*16+15
  f32x4 acc2[4];
#pragma unroll
  for (int b = 0; b < 4; ++b)
#pragma unroll
    for (int c = 0; c < 4; ++c) acc2[b][c] = 0.f;

  for (int s = 0; s < 8; ++s) {
    const unsigned short* p = &hs[w * 16 + r16][s * 32 + g * 4];
    s16x4 lo4 = *reinterpret_cast<const s16x4*>(p);
    s16x4 hi4 = *reinterpret_cast<const s16x4*>(p + 16);
    bf16x8 af;
#pragma unroll
    for (int j = 0; j < 4; ++j) { af[j] = lo4[j]; af[4 + j] = hi4[j]; }
#pragma unroll
    for (int nr = 0; nr < 4; ++nr) {
      bf16x8 bf = *reinterpret_cast<const bf16x8*>(B2p + (size_t)((nr * 8 + s) * 64 + l) * 8);
      acc2[nr] = __builtin_amdgcn_mfma_f32_16x16x32_bf16(af, bf, acc2[nr], 0, 0, 0);
    }
  }
#pragma unroll
  for (int nr = 0; nr < 4; ++nr) {
    int n = nr * 16 + r16;
    float bias = b2[n];
#pragma unroll
    for (int i = 0; i < 4; ++i) {
      int grow = blockIdx.x * 64 + w * 16 + g * 4 + i;
      if (grow < NN) out[(size_t)grow * DO + n] = acc2[nr][i] + bias;
    }
  }
}

extern "C" void kernel_launch(void* const* d_in, const int* in_sizes, int n_in,
                              void* d_out, int out_size, void* d_ws, size_t ws_size,
                              hipStream_t stream) {
  const float* x = (const float*)d_in[0];
  const int* erow = (const int*)d_in[1];
  const int* ecol = (const int*)d_in[2];
  const float* eval_ = (const float*)d_in[3];
  const float* W1 = (const float*)d_in[4];
  const float* b1 = (const float*)d_in[5];
  const float* W2 = (const float*)d_in[6];
  const float* b2 = (const float*)d_in[7];
  float* out = (float*)d_out;

  char* ws = (char*)d_ws;
  size_t o = 0;
  uint* xb = (uint*)(ws + o);          o += (size_t)NN * 64 * 4;   // x bf16, 12.8 MB
  uint* hu = (uint*)(ws + o);          o += (size_t)NN * 64 * 4;   // h bf16, 12.8 MB
  unsigned short* B1p = (unsigned short*)(ws + o); o += 32768 * 2; // 64 KB
  unsigned short* B2p = (unsigned short*)(ws + o); o += 16384 * 2; // 32 KB
  o = (o + 255) & ~(size_t)255;
  int* cnt = (int*)(ws + o);           o += 4096;
  int* hist = (int*)(ws + o);          o += (size_t)NBLK_E * NBUCK * 4;  // 613 KB
  o = (o + 255) & ~(size_t)255;
  uint2* ep = (uint2*)(ws + o);        // NBUCK*CAP*8 = 12.8 MB

  k_cvt<<<3125, 256, 0, stream>>>(x, xb);
  k_histA<<<NBLK_E, 256, 0, stream>>>(erow, hist);
  k_scanB<<<NBUCK, 256, 0, stream>>>(hist, cnt);
  k_scatC<<<NBLK_E, 256, 0, stream>>>(erow, ecol, eval_, hist, ep);
  k_pack<<<24, 256, 0, stream>>>(W1, W2, B1p, B2p);
  k_spmm_bucket<<<NBUCK, 512, 0, stream>>>(xb, ep, cnt, hu);
  k_mlp<<<(NN + 63) / 64, 256, 0, stream>>>((const unsigned short*)hu, B1p, b1,
                                            B2p, b2, out);
}

// Round 9
// 97.118 us; speedup vs baseline: 9.4518x; 1.0600x over previous
//
#include <hip/hip_runtime.h>

#define NN 50000
#define NE 800000
#define DIN 128
#define DH 200
#define DHP 256   // padded hidden
#define DO 64
#define NBUCK 782     // ceil(NN/64)
#define CAP 2048      // bucket capacity; lambda=1023, sigma=32 -> +32 sigma
#define EPB 4096      // edges per histogram/scatter block
#define NBLK_E ((NE + EPB - 1) / EPB)   // 196
#define CVT_B 3125
#define PACK_B 24

typedef float f32x4 __attribute__((ext_vector_type(4)));
typedef short bf16x8 __attribute__((ext_vector_type(8)));
typedef short s16x4 __attribute__((ext_vector_type(4)));
typedef unsigned int uint;

__device__ __forceinline__ unsigned short f2bf(float f) {
  unsigned int b = __float_as_uint(f);
  b = (b + 0x7FFFu + ((b >> 16) & 1u)) >> 16;
  return (unsigned short)b;
}
__device__ __forceinline__ float bf2f(unsigned short u) {
  return __uint_as_float((unsigned int)u << 16);
}

// ---------------- prep: cvt x->bf16 | block-local histogram | pack W -------
__global__ __launch_bounds__(256) void k_prep(const float* __restrict__ x,
                                              uint* __restrict__ xb,
                                              const int* __restrict__ row,
                                              int* __restrict__ hist,
                                              const float* __restrict__ W1,
                                              const float* __restrict__ W2,
                                              unsigned short* __restrict__ B1p,
                                              unsigned short* __restrict__ B2p) {
  __shared__ int lh[NBUCK];
  const int bid = blockIdx.x;
  const int tid = threadIdx.x;
  if (bid < CVT_B) {
    int i = bid * 256 + tid;
    f32x4 a = *reinterpret_cast<const f32x4*>(x + (size_t)i * 8);
    f32x4 b = *reinterpret_cast<const f32x4*>(x + (size_t)i * 8 + 4);
    uint4 o;
    o.x = (uint)f2bf(a[0]) | ((uint)f2bf(a[1]) << 16);
    o.y = (uint)f2bf(a[2]) | ((uint)f2bf(a[3]) << 16);
    o.z = (uint)f2bf(b[0]) | ((uint)f2bf(b[1]) << 16);
    o.w = (uint)f2bf(b[2]) | ((uint)f2bf(b[3]) << 16);
    *reinterpret_cast<uint4*>(xb + (size_t)i * 4) = o;
  } else if (bid < CVT_B + NBLK_E) {
    const int hb = bid - CVT_B;
    const int e0 = hb * EPB;
    for (int j = tid; j < NBUCK; j += 256) lh[j] = 0;
    __syncthreads();
#pragma unroll
    for (int p = 0; p < EPB / 256; ++p) {
      int e = e0 + p * 256 + tid;
      if (e < NE) atomicAdd(&lh[row[e] >> 6], 1);
    }
    __syncthreads();
    int* hrow = hist + (size_t)hb * NBUCK;
    for (int j = tid; j < NBUCK; j += 256) hrow[j] = lh[j];
  } else {
    int gidx = (bid - CVT_B - NBLK_E) * 256 + tid;  // 6144 total
    if (gidx < 4096) {
      int idx = gidx;
      int lane = idx & 63;
      int s = (idx >> 6) & 3;
      int t = idx >> 8;
      int n = t * 16 + (lane & 15);
      unsigned short v[8];
#pragma unroll
      for (int j = 0; j < 8; ++j) {
        int k = s * 32 + (j & 3) + ((lane >> 4) << 2) + ((j >> 2) << 4);
        float f = (n < DH) ? W1[(size_t)k * DH + n] : 0.f;
        v[j] = f2bf(f);
      }
      *reinterpret_cast<uint4*>(B1p + (size_t)idx * 8) =
          *reinterpret_cast<const uint4*>(v);
    } else {
      int idx = gidx - 4096;
      int lane = idx & 63;
      int s = (idx >> 6) & 7;
      int t = idx >> 9;
      int n = t * 16 + (lane & 15);
      unsigned short v[8];
#pragma unroll
      for (int j = 0; j < 8; ++j) {
        int k = s * 32 + (j & 3) + ((lane >> 4) << 2) + ((j >> 2) << 4);
        float f = (k < DH) ? W2[(size_t)k * DO + n] : 0.f;
        v[j] = f2bf(f);
      }
      *reinterpret_cast<uint4*>(B2p + (size_t)idx * 8) =
          *reinterpret_cast<const uint4*>(v);
    }
  }
}

// ---------------- phase B: per-bucket scan across blocks -------------------
__global__ __launch_bounds__(256) void k_scanB(int* __restrict__ hist,
                                               int* __restrict__ cnt) {
  __shared__ int ws[4];
  const int k = blockIdx.x;
  const int tid = threadIdx.x;
  int v = (tid < NBLK_E) ? hist[(size_t)tid * NBUCK + k] : 0;
  int lane = tid & 63, wid = tid >> 6;
  int incl = v;
#pragma unroll
  for (int d = 1; d < 64; d <<= 1) {
    int t = __shfl_up(incl, d, 64);
    if (lane >= d) incl += t;
  }
  if (lane == 63) ws[wid] = incl;
  __syncthreads();
  if (tid == 0) {
    int s = 0;
#pragma unroll
    for (int q = 0; q < 4; ++q) { int xx = ws[q]; ws[q] = s; s += xx; }
  }
  __syncthreads();
  int excl = ws[wid] + incl - v;
  if (tid < NBLK_E) hist[(size_t)tid * NBUCK + k] = excl;
  if (tid == 255) cnt[k] = excl;  // v==0 here -> excl == total
}

// ---------------- phase C: rank + scatter (single-writer segments) ---------
__global__ __launch_bounds__(256) void k_scatC(const int* __restrict__ row,
                                               const int* __restrict__ col,
                                               const float* __restrict__ val,
                                               const int* __restrict__ hist,
                                               uint2* __restrict__ ep) {
  __shared__ int lh[NBUCK];
  __shared__ int lbase[NBUCK];
  const int tid = threadIdx.x;
  const int e0 = blockIdx.x * EPB;
  const int* hrow = hist + (size_t)blockIdx.x * NBUCK;
  for (int j = tid; j < NBUCK; j += 256) { lh[j] = 0; lbase[j] = hrow[j]; }
  __syncthreads();
#pragma unroll
  for (int p = 0; p < EPB / 256; ++p) {
    int e = e0 + p * 256 + tid;
    if (e < NE) {
      int r = row[e];
      int k = r >> 6;
      int rank = atomicAdd(&lh[k], 1);
      int pos = lbase[k] + rank;
      if (pos < CAP)
        ep[(size_t)k * CAP + pos] =
            make_uint2((uint)col[e] | ((uint)(r & 63) << 16), __float_as_uint(val[e]));
    }
  }
}

// ---------------- fused SpMM + MLP: one block per 64-row bucket ------------
// 512 thr (8 waves). Phases: LDS counting-sort of edge records -> register
// gather (h = x + A x, bf16 -> hb LDS) -> stage1 MFMA (hs = relu(hb@W1+b1))
// -> stage2 MFMA (out = hs@W2+b2). hs aliases the dead sort buffer.
__global__ __launch_bounds__(512, 4) void k_spmm_mlp(const uint* __restrict__ xbu,
                                                     const uint2* __restrict__ ep,
                                                     const int* __restrict__ cnt,
                                                     const unsigned short* __restrict__ B1p,
                                                     const float* __restrict__ b1,
                                                     const unsigned short* __restrict__ B2p,
                                                     const float* __restrict__ b2,
                                                     float* __restrict__ out) {
  __shared__ union {
    uint2 se[CAP];                       // 16 KB sorted records
    unsigned short hs[64][DHP + 8];      // 33.8 KB hidden tile (stage1 out)
  } u;
  __shared__ unsigned short hb[64][DIN + 8];  // 17 KB h tile (bf16)
  __shared__ int deg[64], rbase[64], rpos[64];
  const int tid = threadIdx.x;
  const int bucket = blockIdx.x;
  const int r0 = bucket << 6;
  const int w = tid >> 6, lane = tid & 63;

  if (tid < 64) deg[tid] = 0;
  __syncthreads();

  int n = cnt[bucket];
  if (n > CAP) n = CAP;
  const uint2* eb = ep + (size_t)bucket * CAP;

  // pass 1: per-row counts
  for (int j = tid; j < n; j += 512) {
    uint2 e = eb[j];
    atomicAdd(&deg[(e.x >> 16) & 63], 1);
  }
  __syncthreads();

  // wave 0: exclusive scan of 64 degrees
  if (tid < 64) {
    int v = deg[tid];
    int incl = v;
#pragma unroll
    for (int d = 1; d < 64; d <<= 1) {
      int t = __shfl_up(incl, d, 64);
      if (tid >= d) incl += t;
    }
    rbase[tid] = incl - v;
    rpos[tid] = incl - v;
  }
  __syncthreads();

  // pass 2: scatter records row-sorted into LDS
  for (int j = tid; j < n; j += 512) {
    uint2 e = eb[j];
    int lr = (e.x >> 16) & 63;
    int p = atomicAdd(&rpos[lr], 1);
    u.se[p] = make_uint2(e.x & 0xFFFFu, e.y);
  }
  __syncthreads();

  // gather: wave w owns rows w, w+8, ..., w+56; lane owns 2 features
  for (int rr = w; rr < 64; rr += 8) {
    int gr = r0 + rr;
    if (gr >= NN) {
      *reinterpret_cast<uint*>(&hb[rr][2 * lane]) = 0u;
      continue;
    }
    int s = rbase[rr];
    int en = s + deg[rr];
    float ax = 0.f, ay = 0.f;
    int j = s;
    for (; j + 3 < en; j += 4) {
      uint2 e0 = u.se[j], e1 = u.se[j + 1], e2 = u.se[j + 2], e3 = u.se[j + 3];
      uint a0 = xbu[(size_t)e0.x * 64 + lane];
      uint a1 = xbu[(size_t)e1.x * 64 + lane];
      uint a2 = xbu[(size_t)e2.x * 64 + lane];
      uint a3 = xbu[(size_t)e3.x * 64 + lane];
      float v0 = __uint_as_float(e0.y), v1 = __uint_as_float(e1.y);
      float v2 = __uint_as_float(e2.y), v3 = __uint_as_float(e3.y);
      ax += v0 * bf2f((unsigned short)a0) + v1 * bf2f((unsigned short)a1) +
            v2 * bf2f((unsigned short)a2) + v3 * bf2f((unsigned short)a3);
      ay += v0 * bf2f((unsigned short)(a0 >> 16)) + v1 * bf2f((unsigned short)(a1 >> 16)) +
            v2 * bf2f((unsigned short)(a2 >> 16)) + v3 * bf2f((unsigned short)(a3 >> 16));
    }
    for (; j < en; ++j) {
      uint2 e0 = u.se[j];
      uint a0 = xbu[(size_t)e0.x * 64 + lane];
      float v0 = __uint_as_float(e0.y);
      ax += v0 * bf2f((unsigned short)a0);
      ay += v0 * bf2f((unsigned short)(a0 >> 16));
    }
    uint xs = xbu[(size_t)gr * 64 + lane];
    ax += bf2f((unsigned short)xs);
    ay += bf2f((unsigned short)(xs >> 16));
    *reinterpret_cast<uint*>(&hb[rr][2 * lane]) =
        (uint)f2bf(ax) | ((uint)f2bf(ay) << 16);
  }
  __syncthreads();   // hb ready; se dead from here on

  // ---- stage 1: hs = relu(hb @ W1 + b1); 8 waves = 2M x 4N, tile 32x64 ----
  const int wm = w >> 2, wn = w & 3;
  const int g = lane >> 4, r16 = lane & 15;
  f32x4 acc[2][4];
#pragma unroll
  for (int a = 0; a < 2; ++a)
#pragma unroll
    for (int b = 0; b < 4; ++b)
#pragma unroll
      for (int c = 0; c < 4; ++c) acc[a][b][c] = 0.f;

  for (int s = 0; s < 4; ++s) {
    bf16x8 af[2];
#pragma unroll
    for (int mr = 0; mr < 2; ++mr) {
      const unsigned short* p = &hb[wm * 32 + mr * 16 + r16][s * 32 + g * 4];
      s16x4 lo4 = *reinterpret_cast<const s16x4*>(p);
      s16x4 hi4 = *reinterpret_cast<const s16x4*>(p + 16);
#pragma unroll
      for (int j = 0; j < 4; ++j) { af[mr][j] = lo4[j]; af[mr][4 + j] = hi4[j]; }
    }
#pragma unroll
    for (int nr = 0; nr < 4; ++nr) {
      int t = wn * 4 + nr;
      bf16x8 bf = *reinterpret_cast<const bf16x8*>(B1p + (size_t)((t * 4 + s) * 64 + lane) * 8);
      acc[0][nr] = __builtin_amdgcn_mfma_f32_16x16x32_bf16(af[0], bf, acc[0][nr], 0, 0, 0);
      acc[1][nr] = __builtin_amdgcn_mfma_f32_16x16x32_bf16(af[1], bf, acc[1][nr], 0, 0, 0);
    }
  }
  __syncthreads();   // all reads of hb done? (hb not aliased; this sync guards hs alias of se)
#pragma unroll
  for (int mr = 0; mr < 2; ++mr)
#pragma unroll
    for (int nr = 0; nr < 4; ++nr) {
      int nn = wn * 64 + nr * 16 + r16;
      float bias = (nn < DH) ? b1[nn] : 0.f;
#pragma unroll
      for (int i = 0; i < 4; ++i) {
        int rl = wm * 32 + mr * 16 + g * 4 + i;
        float v = acc[mr][nr][i] + bias;
        v = v > 0.f ? v : 0.f;
        if (nn >= DH) v = 0.f;
        u.hs[rl][nn] = f2bf(v);
      }
    }
  __syncthreads();

  // ---- stage 2: out = hs @ W2 + b2; wave w: m-tile w>>1, n-tiles (w&1)*2+q -
  const int mt = w >> 1;
  const int nt2 = (w & 1) * 2;
  f32x4 acc2[2];
#pragma unroll
  for (int b = 0; b < 2; ++b)
#pragma unroll
    for (int c = 0; c < 4; ++c) acc2[b][c] = 0.f;

  for (int s = 0; s < 8; ++s) {
    const unsigned short* p = &u.hs[mt * 16 + r16][s * 32 + g * 4];
    s16x4 lo4 = *reinterpret_cast<const s16x4*>(p);
    s16x4 hi4 = *reinterpret_cast<const s16x4*>(p + 16);
    bf16x8 af;
#pragma unroll
    for (int j = 0; j < 4; ++j) { af[j] = lo4[j]; af[4 + j] = hi4[j]; }
#pragma unroll
    for (int q = 0; q < 2; ++q) {
      int nt = nt2 + q;
      bf16x8 bf = *reinterpret_cast<const bf16x8*>(B2p + (size_t)((nt * 8 + s) * 64 + lane) * 8);
      acc2[q] = __builtin_amdgcn_mfma_f32_16x16x32_bf16(af, bf, acc2[q], 0, 0, 0);
    }
  }
#pragma unroll
  for (int q = 0; q < 2; ++q) {
    int nn = (nt2 + q) * 16 + r16;
    float bias = b2[nn];
#pragma unroll
    for (int i = 0; i < 4; ++i) {
      int grow = r0 + mt * 16 + g * 4 + i;
      if (grow < NN) out[(size_t)grow * DO + nn] = acc2[q][i] + bias;
    }
  }
}

extern "C" void kernel_launch(void* const* d_in, const int* in_sizes, int n_in,
                              void* d_out, int out_size, void* d_ws, size_t ws_size,
                              hipStream_t stream) {
  const float* x = (const float*)d_in[0];
  const int* erow = (const int*)d_in[1];
  const int* ecol = (const int*)d_in[2];
  const float* eval_ = (const float*)d_in[3];
  const float* W1 = (const float*)d_in[4];
  const float* b1 = (const float*)d_in[5];
  const float* W2 = (const float*)d_in[6];
  const float* b2 = (const float*)d_in[7];
  float* out = (float*)d_out;

  char* ws = (char*)d_ws;
  size_t o = 0;
  uint* xb = (uint*)(ws + o);          o += (size_t)NN * 64 * 4;   // x bf16, 12.8 MB
  unsigned short* B1p = (unsigned short*)(ws + o); o += 32768 * 2; // 64 KB
  unsigned short* B2p = (unsigned short*)(ws + o); o += 16384 * 2; // 32 KB
  o = (o + 255) & ~(size_t)255;
  int* cnt = (int*)(ws + o);           o += 4096;
  int* hist = (int*)(ws + o);          o += (size_t)NBLK_E * NBUCK * 4;  // 613 KB
  o = (o + 255) & ~(size_t)255;
  uint2* ep = (uint2*)(ws + o);        // NBUCK*CAP*8 = 12.8 MB

  k_prep<<<CVT_B + NBLK_E + PACK_B, 256, 0, stream>>>(x, xb, erow, hist, W1, W2, B1p, B2p);
  k_scanB<<<NBUCK, 256, 0, stream>>>(hist, cnt);
  k_scatC<<<NBLK_E, 256, 0, stream>>>(erow, ecol, eval_, hist, ep);
  k_spmm_mlp<<<NBUCK, 512, 0, stream>>>(xb, ep, cnt, B1p, b1, B2p, b2, out);
}

// Round 10
// 80.622 us; speedup vs baseline: 11.3857x; 1.2046x over previous
//
#include <hip/hip_runtime.h>

#define NN 50000
#define NE 800000
#define DIN 128
#define DH 200
#define DHP 256   // padded hidden
#define DO 64
#define RPB 32        // rows per bucket
#define NBUCK 1564    // ceil(NN/32)
#define CAP 1024      // bucket capacity; lambda=512, sigma=22.6 -> +22 sigma
#define EPB 4096      // edges per histogram/scatter block
#define NBLK_E ((NE + EPB - 1) / EPB)   // 196
#define CVT_B 3125
#define PACK_B 24

typedef float f32x4 __attribute__((ext_vector_type(4)));
typedef short bf16x8 __attribute__((ext_vector_type(8)));
typedef short s16x4 __attribute__((ext_vector_type(4)));
typedef unsigned int uint;

__device__ __forceinline__ unsigned short f2bf(float f) {
  unsigned int b = __float_as_uint(f);
  b = (b + 0x7FFFu + ((b >> 16) & 1u)) >> 16;
  return (unsigned short)b;
}
__device__ __forceinline__ float bf2f(unsigned short u) {
  return __uint_as_float((unsigned int)u << 16);
}

// ---------------- prep: cvt x->bf16 | block-local histogram | pack W -------
__global__ __launch_bounds__(256) void k_prep(const float* __restrict__ x,
                                              uint* __restrict__ xb,
                                              const int* __restrict__ row,
                                              int* __restrict__ hist,
                                              const float* __restrict__ W1,
                                              const float* __restrict__ W2,
                                              unsigned short* __restrict__ B1p,
                                              unsigned short* __restrict__ B2p) {
  __shared__ int lh[NBUCK];
  const int bid = blockIdx.x;
  const int tid = threadIdx.x;
  if (bid < CVT_B) {
    int i = bid * 256 + tid;
    f32x4 a = *reinterpret_cast<const f32x4*>(x + (size_t)i * 8);
    f32x4 b = *reinterpret_cast<const f32x4*>(x + (size_t)i * 8 + 4);
    uint4 o;
    o.x = (uint)f2bf(a[0]) | ((uint)f2bf(a[1]) << 16);
    o.y = (uint)f2bf(a[2]) | ((uint)f2bf(a[3]) << 16);
    o.z = (uint)f2bf(b[0]) | ((uint)f2bf(b[1]) << 16);
    o.w = (uint)f2bf(b[2]) | ((uint)f2bf(b[3]) << 16);
    *reinterpret_cast<uint4*>(xb + (size_t)i * 4) = o;
  } else if (bid < CVT_B + NBLK_E) {
    const int hb = bid - CVT_B;
    const int e0 = hb * EPB;
    for (int j = tid; j < NBUCK; j += 256) lh[j] = 0;
    __syncthreads();
#pragma unroll
    for (int p = 0; p < EPB / 256; ++p) {
      int e = e0 + p * 256 + tid;
      if (e < NE) atomicAdd(&lh[row[e] / RPB], 1);
    }
    __syncthreads();
    int* hrow = hist + (size_t)hb * NBUCK;
    for (int j = tid; j < NBUCK; j += 256) hrow[j] = lh[j];
  } else {
    int gidx = (bid - CVT_B - NBLK_E) * 256 + tid;  // 6144 total
    if (gidx < 4096) {
      int idx = gidx;
      int lane = idx & 63;
      int s = (idx >> 6) & 3;
      int t = idx >> 8;
      int n = t * 16 + (lane & 15);
      unsigned short v[8];
#pragma unroll
      for (int j = 0; j < 8; ++j) {
        int k = s * 32 + (j & 3) + ((lane >> 4) << 2) + ((j >> 2) << 4);
        float f = (n < DH) ? W1[(size_t)k * DH + n] : 0.f;
        v[j] = f2bf(f);
      }
      *reinterpret_cast<uint4*>(B1p + (size_t)idx * 8) =
          *reinterpret_cast<const uint4*>(v);
    } else {
      int idx = gidx - 4096;
      int lane = idx & 63;
      int s = (idx >> 6) & 7;
      int t = idx >> 9;
      int n = t * 16 + (lane & 15);
      unsigned short v[8];
#pragma unroll
      for (int j = 0; j < 8; ++j) {
        int k = s * 32 + (j & 3) + ((lane >> 4) << 2) + ((j >> 2) << 4);
        float f = (k < DH) ? W2[(size_t)k * DO + n] : 0.f;
        v[j] = f2bf(f);
      }
      *reinterpret_cast<uint4*>(B2p + (size_t)idx * 8) =
          *reinterpret_cast<const uint4*>(v);
    }
  }
}

// ---------------- phase B: per-bucket scan across blocks -------------------
__global__ __launch_bounds__(256) void k_scanB(int* __restrict__ hist,
                                               int* __restrict__ cnt) {
  __shared__ int ws[4];
  const int k = blockIdx.x;
  const int tid = threadIdx.x;
  int v = (tid < NBLK_E) ? hist[(size_t)tid * NBUCK + k] : 0;
  int lane = tid & 63, wid = tid >> 6;
  int incl = v;
#pragma unroll
  for (int d = 1; d < 64; d <<= 1) {
    int t = __shfl_up(incl, d, 64);
    if (lane >= d) incl += t;
  }
  if (lane == 63) ws[wid] = incl;
  __syncthreads();
  if (tid == 0) {
    int s = 0;
#pragma unroll
    for (int q = 0; q < 4; ++q) { int xx = ws[q]; ws[q] = s; s += xx; }
  }
  __syncthreads();
  int excl = ws[wid] + incl - v;
  if (tid < NBLK_E) hist[(size_t)tid * NBUCK + k] = excl;
  if (tid == 255) cnt[k] = excl;  // v==0 here -> excl == total
}

// ---------------- phase C: rank + scatter (single-writer segments) ---------
__global__ __launch_bounds__(256) void k_scatC(const int* __restrict__ row,
                                               const int* __restrict__ col,
                                               const float* __restrict__ val,
                                               const int* __restrict__ hist,
                                               uint2* __restrict__ ep) {
  __shared__ int lh[NBUCK];
  __shared__ int lbase[NBUCK];
  const int tid = threadIdx.x;
  const int e0 = blockIdx.x * EPB;
  const int* hrow = hist + (size_t)blockIdx.x * NBUCK;
  for (int j = tid; j < NBUCK; j += 256) { lh[j] = 0; lbase[j] = hrow[j]; }
  __syncthreads();
#pragma unroll
  for (int p = 0; p < EPB / 256; ++p) {
    int e = e0 + p * 256 + tid;
    if (e < NE) {
      int r = row[e];
      int k = r / RPB;
      int rank = atomicAdd(&lh[k], 1);
      int pos = lbase[k] + rank;
      if (pos < CAP)
        ep[(size_t)k * CAP + pos] =
            make_uint2((uint)col[e] | ((uint)(r & (RPB - 1)) << 16),
                       __float_as_uint(val[e]));
    }
  }
}

// ---------------- fused SpMM + MLP: one block per 32-row bucket ------------
// 256 thr (4 waves), 8 blocks/CU target. Phases: LDS counting-sort ->
// register gather (h tile, bf16) -> stage1 MFMA (hs = relu(hb@W1+b1)) ->
// stage2 MFMA (out = hs@W2+b2). hs aliases se+hb via one shared buffer.
__global__ __launch_bounds__(256, 8) void k_spmm_mlp(const uint* __restrict__ xbu,
                                                     const uint2* __restrict__ ep,
                                                     const int* __restrict__ cnt,
                                                     const unsigned short* __restrict__ B1p,
                                                     const float* __restrict__ b1,
                                                     const unsigned short* __restrict__ B2p,
                                                     const float* __restrict__ b2,
                                                     float* __restrict__ out) {
  __shared__ uint2 buf2[2112];  // 16896 B
  __shared__ int deg[RPB], rbase[RPB], rpos[RPB];
  uint2* se = buf2;                                       // [CAP]   8192 B
  unsigned short* hb = (unsigned short*)(buf2 + CAP);     // [32][136] 8704 B
  unsigned short* hs = (unsigned short*)buf2;             // [32][260] 16640 B (aliases se+hb)
  const int tid = threadIdx.x;
  const int bucket = blockIdx.x;
  const int r0 = bucket * RPB;
  const int w = tid >> 6, lane = tid & 63;
  const int g = lane >> 4, r16 = lane & 15;

  if (tid < RPB) deg[tid] = 0;
  __syncthreads();

  int n = cnt[bucket];
  if (n > CAP) n = CAP;
  const uint2* eb = ep + (size_t)bucket * CAP;

  // pass 1: per-row counts
  for (int j = tid; j < n; j += 256)
    atomicAdd(&deg[(eb[j].x >> 16) & (RPB - 1)], 1);
  __syncthreads();

  // lanes 0..31 of wave 0: exclusive scan of 32 degrees
  if (tid < RPB) {
    int v = deg[tid];
    int incl = v;
#pragma unroll
    for (int d = 1; d < RPB; d <<= 1) {
      int t = __shfl_up(incl, d, 64);
      if (tid >= d) incl += t;
    }
    rbase[tid] = incl - v;
    rpos[tid] = incl - v;
  }
  __syncthreads();

  // pass 2: scatter records row-sorted into LDS
  for (int j = tid; j < n; j += 256) {
    uint2 e = eb[j];
    int lr = (e.x >> 16) & (RPB - 1);
    int p = atomicAdd(&rpos[lr], 1);
    se[p] = make_uint2(e.x & 0xFFFFu, e.y);
  }
  __syncthreads();

  // gather: wave w owns rows w, w+4, ..., w+28; lane owns 2 features
  for (int rr = w; rr < RPB; rr += 4) {
    int gr = r0 + rr;
    if (gr >= NN) {
      *reinterpret_cast<uint*>(&hb[rr * 136 + 2 * lane]) = 0u;
      continue;
    }
    int s = rbase[rr];
    int en = s + deg[rr];
    float ax = 0.f, ay = 0.f;
    int j = s;
    for (; j + 3 < en; j += 4) {
      uint2 e0 = se[j], e1 = se[j + 1], e2 = se[j + 2], e3 = se[j + 3];
      uint a0 = xbu[(size_t)e0.x * 64 + lane];
      uint a1 = xbu[(size_t)e1.x * 64 + lane];
      uint a2 = xbu[(size_t)e2.x * 64 + lane];
      uint a3 = xbu[(size_t)e3.x * 64 + lane];
      float v0 = __uint_as_float(e0.y), v1 = __uint_as_float(e1.y);
      float v2 = __uint_as_float(e2.y), v3 = __uint_as_float(e3.y);
      ax += v0 * bf2f((unsigned short)a0) + v1 * bf2f((unsigned short)a1) +
            v2 * bf2f((unsigned short)a2) + v3 * bf2f((unsigned short)a3);
      ay += v0 * bf2f((unsigned short)(a0 >> 16)) + v1 * bf2f((unsigned short)(a1 >> 16)) +
            v2 * bf2f((unsigned short)(a2 >> 16)) + v3 * bf2f((unsigned short)(a3 >> 16));
    }
    for (; j < en; ++j) {
      uint2 e0 = se[j];
      uint a0 = xbu[(size_t)e0.x * 64 + lane];
      float v0 = __uint_as_float(e0.y);
      ax += v0 * bf2f((unsigned short)a0);
      ay += v0 * bf2f((unsigned short)(a0 >> 16));
    }
    uint xs = xbu[(size_t)gr * 64 + lane];
    ax += bf2f((unsigned short)xs);
    ay += bf2f((unsigned short)(xs >> 16));
    *reinterpret_cast<uint*>(&hb[rr * 136 + 2 * lane]) =
        (uint)f2bf(ax) | ((uint)f2bf(ay) << 16);
  }
  __syncthreads();   // hb ready; se dead from here on

  // ---- stage 1: hs = relu(hb @ W1 + b1); wave w = n-tiles w*4..w*4+3 ------
  f32x4 acc[2][4];
#pragma unroll
  for (int a = 0; a < 2; ++a)
#pragma unroll
    for (int b = 0; b < 4; ++b)
#pragma unroll
      for (int c = 0; c < 4; ++c) acc[a][b][c] = 0.f;

  for (int s = 0; s < 4; ++s) {
    bf16x8 af[2];
#pragma unroll
    for (int mr = 0; mr < 2; ++mr) {
      const unsigned short* p = &hb[(mr * 16 + r16) * 136 + s * 32 + g * 4];
      s16x4 lo4 = *reinterpret_cast<const s16x4*>(p);
      s16x4 hi4 = *reinterpret_cast<const s16x4*>(p + 16);
#pragma unroll
      for (int j = 0; j < 4; ++j) { af[mr][j] = lo4[j]; af[mr][4 + j] = hi4[j]; }
    }
#pragma unroll
    for (int nr = 0; nr < 4; ++nr) {
      int t = w * 4 + nr;
      bf16x8 bf = *reinterpret_cast<const bf16x8*>(B1p + (size_t)((t * 4 + s) * 64 + lane) * 8);
      acc[0][nr] = __builtin_amdgcn_mfma_f32_16x16x32_bf16(af[0], bf, acc[0][nr], 0, 0, 0);
      acc[1][nr] = __builtin_amdgcn_mfma_f32_16x16x32_bf16(af[1], bf, acc[1][nr], 0, 0, 0);
    }
  }
  __syncthreads();   // all hb reads done; hs may now overwrite se+hb
#pragma unroll
  for (int mr = 0; mr < 2; ++mr)
#pragma unroll
    for (int nr = 0; nr < 4; ++nr) {
      int nn = w * 64 + nr * 16 + r16;
      float bias = (nn < DH) ? b1[nn] : 0.f;
#pragma unroll
      for (int i = 0; i < 4; ++i) {
        int rl = mr * 16 + g * 4 + i;
        float v = acc[mr][nr][i] + bias;
        v = v > 0.f ? v : 0.f;
        if (nn >= DH) v = 0.f;
        hs[rl * 260 + nn] = f2bf(v);
      }
    }
  __syncthreads();

  // ---- stage 2: out = hs @ W2 + b2; wave w = n-tile w, m-tiles 0..1 -------
  f32x4 acc2[2];
#pragma unroll
  for (int b = 0; b < 2; ++b)
#pragma unroll
    for (int c = 0; c < 4; ++c) acc2[b][c] = 0.f;

  for (int s = 0; s < 8; ++s) {
#pragma unroll
    for (int mt = 0; mt < 2; ++mt) {
      const unsigned short* p = &hs[(mt * 16 + r16) * 260 + s * 32 + g * 4];
      s16x4 lo4 = *reinterpret_cast<const s16x4*>(p);
      s16x4 hi4 = *reinterpret_cast<const s16x4*>(p + 16);
      bf16x8 af;
#pragma unroll
      for (int j = 0; j < 4; ++j) { af[j] = lo4[j]; af[4 + j] = hi4[j]; }
      bf16x8 bf = *reinterpret_cast<const bf16x8*>(B2p + (size_t)((w * 8 + s) * 64 + lane) * 8);
      acc2[mt] = __builtin_amdgcn_mfma_f32_16x16x32_bf16(af, bf, acc2[mt], 0, 0, 0);
    }
  }
#pragma unroll
  for (int mt = 0; mt < 2; ++mt) {
    int nn = w * 16 + r16;
    float bias = b2[nn];
#pragma unroll
    for (int i = 0; i < 4; ++i) {
      int grow = r0 + mt * 16 + g * 4 + i;
      if (grow < NN) out[(size_t)grow * DO + nn] = acc2[mt][i] + bias;
    }
  }
}

extern "C" void kernel_launch(void* const* d_in, const int* in_sizes, int n_in,
                              void* d_out, int out_size, void* d_ws, size_t ws_size,
                              hipStream_t stream) {
  const float* x = (const float*)d_in[0];
  const int* erow = (const int*)d_in[1];
  const int* ecol = (const int*)d_in[2];
  const float* eval_ = (const float*)d_in[3];
  const float* W1 = (const float*)d_in[4];
  const float* b1 = (const float*)d_in[5];
  const float* W2 = (const float*)d_in[6];
  const float* b2 = (const float*)d_in[7];
  float* out = (float*)d_out;

  char* ws = (char*)d_ws;
  size_t o = 0;
  uint* xb = (uint*)(ws + o);          o += (size_t)NN * 64 * 4;   // x bf16, 12.8 MB
  unsigned short* B1p = (unsigned short*)(ws + o); o += 32768 * 2; // 64 KB
  unsigned short* B2p = (unsigned short*)(ws + o); o += 16384 * 2; // 32 KB
  o = (o + 255) & ~(size_t)255;
  int* cnt = (int*)(ws + o);           o += (NBUCK * 4 + 255) & ~(size_t)255;
  int* hist = (int*)(ws + o);          o += (size_t)NBLK_E * NBUCK * 4;  // 1.23 MB
  o = (o + 255) & ~(size_t)255;
  uint2* ep = (uint2*)(ws + o);        // NBUCK*CAP*8 = 12.8 MB

  k_prep<<<CVT_B + NBLK_E + PACK_B, 256, 0, stream>>>(x, xb, erow, hist, W1, W2, B1p, B2p);
  k_scanB<<<NBUCK, 256, 0, stream>>>(hist, cnt);
  k_scatC<<<NBLK_E, 256, 0, stream>>>(erow, ecol, eval_, hist, ep);
  k_spmm_mlp<<<NBUCK, 256, 0, stream>>>(xb, ep, cnt, B1p, b1, B2p, b2, out);
}

// Round 11
// 78.481 us; speedup vs baseline: 11.6964x; 1.0273x over previous
//
#include <hip/hip_runtime.h>

#define NN 50000
#define NE 800000
#define DIN 128
#define DH 200
#define DHP 256   // padded hidden
#define DO 64
#define RPB 32        // rows per bucket
#define NBUCK 1564    // ceil(NN/32)
#define CAP 1024      // bucket capacity; lambda=512, sigma=22.6 -> +22 sigma
#define EPB 4096      // edges per histogram/scatter block
#define NBLK_E ((NE + EPB - 1) / EPB)   // 196
#define CVT_B 3125
#define PACK_B 24

typedef float f32x4 __attribute__((ext_vector_type(4)));
typedef short bf16x8 __attribute__((ext_vector_type(8)));
typedef short s16x4 __attribute__((ext_vector_type(4)));
typedef unsigned int uint;

__device__ __forceinline__ unsigned short f2bf(float f) {
  unsigned int b = __float_as_uint(f);
  b = (b + 0x7FFFu + ((b >> 16) & 1u)) >> 16;
  return (unsigned short)b;
}
__device__ __forceinline__ float bf2f(unsigned short u) {
  return __uint_as_float((unsigned int)u << 16);
}

// ---------------- prep: cvt x->bf16 | block-local histogram | pack W -------
__global__ __launch_bounds__(256) void k_prep(const float* __restrict__ x,
                                              uint* __restrict__ xb,
                                              const int* __restrict__ row,
                                              int* __restrict__ hist,
                                              const float* __restrict__ W1,
                                              const float* __restrict__ W2,
                                              unsigned short* __restrict__ B1p,
                                              unsigned short* __restrict__ B2p) {
  __shared__ int lh[NBUCK];
  const int bid = blockIdx.x;
  const int tid = threadIdx.x;
  if (bid < CVT_B) {
    int i = bid * 256 + tid;
    f32x4 a = *reinterpret_cast<const f32x4*>(x + (size_t)i * 8);
    f32x4 b = *reinterpret_cast<const f32x4*>(x + (size_t)i * 8 + 4);
    uint4 o;
    o.x = (uint)f2bf(a[0]) | ((uint)f2bf(a[1]) << 16);
    o.y = (uint)f2bf(a[2]) | ((uint)f2bf(a[3]) << 16);
    o.z = (uint)f2bf(b[0]) | ((uint)f2bf(b[1]) << 16);
    o.w = (uint)f2bf(b[2]) | ((uint)f2bf(b[3]) << 16);
    *reinterpret_cast<uint4*>(xb + (size_t)i * 4) = o;
  } else if (bid < CVT_B + NBLK_E) {
    const int hb = bid - CVT_B;
    const int e0 = hb * EPB;
    for (int j = tid; j < NBUCK; j += 256) lh[j] = 0;
    __syncthreads();
#pragma unroll
    for (int p = 0; p < EPB / 256; ++p) {
      int e = e0 + p * 256 + tid;
      if (e < NE) atomicAdd(&lh[row[e] / RPB], 1);
    }
    __syncthreads();
    int* hrow = hist + (size_t)hb * NBUCK;
    for (int j = tid; j < NBUCK; j += 256) hrow[j] = lh[j];
  } else {
    int gidx = (bid - CVT_B - NBLK_E) * 256 + tid;  // 6144 total
    if (gidx < 4096) {
      int idx = gidx;
      int lane = idx & 63;
      int s = (idx >> 6) & 3;
      int t = idx >> 8;
      int n = t * 16 + (lane & 15);
      unsigned short v[8];
#pragma unroll
      for (int j = 0; j < 8; ++j) {
        int k = s * 32 + (j & 3) + ((lane >> 4) << 2) + ((j >> 2) << 4);
        float f = (n < DH) ? W1[(size_t)k * DH + n] : 0.f;
        v[j] = f2bf(f);
      }
      *reinterpret_cast<uint4*>(B1p + (size_t)idx * 8) =
          *reinterpret_cast<const uint4*>(v);
    } else {
      int idx = gidx - 4096;
      int lane = idx & 63;
      int s = (idx >> 6) & 7;
      int t = idx >> 9;
      int n = t * 16 + (lane & 15);
      unsigned short v[8];
#pragma unroll
      for (int j = 0; j < 8; ++j) {
        int k = s * 32 + (j & 3) + ((lane >> 4) << 2) + ((j >> 2) << 4);
        float f = (k < DH) ? W2[(size_t)k * DO + n] : 0.f;
        v[j] = f2bf(f);
      }
      *reinterpret_cast<uint4*>(B2p + (size_t)idx * 8) =
          *reinterpret_cast<const uint4*>(v);
    }
  }
}

// ---------------- phase B: per-bucket scan across blocks -------------------
__global__ __launch_bounds__(256) void k_scanB(int* __restrict__ hist,
                                               int* __restrict__ cnt) {
  __shared__ int ws[4];
  const int k = blockIdx.x;
  const int tid = threadIdx.x;
  int v = (tid < NBLK_E) ? hist[(size_t)tid * NBUCK + k] : 0;
  int lane = tid & 63, wid = tid >> 6;
  int incl = v;
#pragma unroll
  for (int d = 1; d < 64; d <<= 1) {
    int t = __shfl_up(incl, d, 64);
    if (lane >= d) incl += t;
  }
  if (lane == 63) ws[wid] = incl;
  __syncthreads();
  if (tid == 0) {
    int s = 0;
#pragma unroll
    for (int q = 0; q < 4; ++q) { int xx = ws[q]; ws[q] = s; s += xx; }
  }
  __syncthreads();
  int excl = ws[wid] + incl - v;
  if (tid < NBLK_E) hist[(size_t)tid * NBUCK + k] = excl;
  if (tid == 255) cnt[k] = excl;  // v==0 here -> excl == total
}

// ---------------- phase C: rank + scatter (single-writer segments) ---------
__global__ __launch_bounds__(256) void k_scatC(const int* __restrict__ row,
                                               const int* __restrict__ col,
                                               const float* __restrict__ val,
                                               const int* __restrict__ hist,
                                               uint2* __restrict__ ep) {
  __shared__ int lh[NBUCK];
  __shared__ int lbase[NBUCK];
  const int tid = threadIdx.x;
  const int e0 = blockIdx.x * EPB;
  const int* hrow = hist + (size_t)blockIdx.x * NBUCK;
  for (int j = tid; j < NBUCK; j += 256) { lh[j] = 0; lbase[j] = hrow[j]; }
  __syncthreads();
#pragma unroll
  for (int p = 0; p < EPB / 256; ++p) {
    int e = e0 + p * 256 + tid;
    if (e < NE) {
      int r = row[e];
      int k = r / RPB;
      int rank = atomicAdd(&lh[k], 1);
      int pos = lbase[k] + rank;
      if (pos < CAP)
        ep[(size_t)k * CAP + pos] =
            make_uint2((uint)col[e] | ((uint)(r & (RPB - 1)) << 16),
                       __float_as_uint(val[e]));
    }
  }
}

// ---------------- fused SpMM + MLP: one block per 32-row bucket ------------
// 256 thr (4 waves). Records loaded once to registers; in-LDS counting sort;
// half-wave paired gather (2 edges/wave-step, uint2 loads); MFMA MLP.
__global__ __launch_bounds__(256, 8) void k_spmm_mlp(const uint* __restrict__ xbu,
                                                     const uint2* __restrict__ ep,
                                                     const int* __restrict__ cnt,
                                                     const unsigned short* __restrict__ B1p,
                                                     const float* __restrict__ b1,
                                                     const unsigned short* __restrict__ B2p,
                                                     const float* __restrict__ b2,
                                                     float* __restrict__ out) {
  __shared__ uint2 buf2[2112];  // 16896 B
  __shared__ int deg[RPB], rbase[RPB], rpos[RPB];
  uint2* se = buf2;                                       // [CAP]   8192 B
  unsigned short* hb = (unsigned short*)(buf2 + CAP);     // [32][136] 8704 B
  unsigned short* hs = (unsigned short*)buf2;             // [32][260] 16640 B (aliases se+hb)
  const int tid = threadIdx.x;
  const int bucket = blockIdx.x;
  const int r0 = bucket * RPB;
  const int w = tid >> 6, lane = tid & 63;
  const int g = lane >> 4, r16 = lane & 15;
  const int half = lane >> 5, l32 = lane & 31;

  if (tid < RPB) deg[tid] = 0;
  __syncthreads();

  int n = cnt[bucket];
  if (n > CAP) n = CAP;
  const uint2* eb = ep + (size_t)bucket * CAP;

  // load this bucket's records once into registers (4 per thread)
  uint2 rec[4];
  int lr[4];
#pragma unroll
  for (int q = 0; q < 4; ++q) {
    int j = q * 256 + tid;
    rec[q] = (j < n) ? eb[j] : make_uint2(0u, 0u);
    lr[q] = (rec[q].x >> 16) & (RPB - 1);
  }
  // pass 1: per-row counts
#pragma unroll
  for (int q = 0; q < 4; ++q)
    if (q * 256 + tid < n) atomicAdd(&deg[lr[q]], 1);
  __syncthreads();

  // lanes 0..31 of wave 0: exclusive scan of 32 degrees
  if (tid < RPB) {
    int v = deg[tid];
    int incl = v;
#pragma unroll
    for (int d = 1; d < RPB; d <<= 1) {
      int t = __shfl_up(incl, d, 64);
      if (tid >= d) incl += t;
    }
    rbase[tid] = incl - v;
    rpos[tid] = incl - v;
  }
  __syncthreads();

  // pass 2: scatter records row-sorted into LDS
#pragma unroll
  for (int q = 0; q < 4; ++q)
    if (q * 256 + tid < n) {
      int p = atomicAdd(&rpos[lr[q]], 1);
      se[p] = make_uint2(rec[q].x & 0xFFFFu, rec[q].y);
    }
  __syncthreads();

  // gather: wave w owns rows w, w+4, ..., w+28.
  // Half-wave pairing: lanes 0-31 take even slot, 32-63 odd slot; each lane
  // loads uint2 = 4 bf16 features (4*l32 .. 4*l32+3).
  const uint2* xb2 = reinterpret_cast<const uint2*>(xbu);
  for (int rr = w; rr < RPB; rr += 4) {
    int gr = r0 + rr;
    if (gr >= NN) {
      if (half == 0)
        *reinterpret_cast<uint2*>(&hb[rr * 136 + 4 * l32]) = make_uint2(0u, 0u);
      continue;
    }
    int s = rbase[rr];
    int en = s + deg[rr];
    float a0 = 0.f, a1 = 0.f, a2 = 0.f, a3 = 0.f;
    int j = s + half;
    for (; j + 6 < en; j += 8) {
      uint2 e0 = se[j], e1 = se[j + 2], e2 = se[j + 4], e3 = se[j + 6];
      uint2 q0 = xb2[(size_t)e0.x * 32 + l32];
      uint2 q1 = xb2[(size_t)e1.x * 32 + l32];
      uint2 q2 = xb2[(size_t)e2.x * 32 + l32];
      uint2 q3 = xb2[(size_t)e3.x * 32 + l32];
      float v0 = __uint_as_float(e0.y), v1 = __uint_as_float(e1.y);
      float v2 = __uint_as_float(e2.y), v3 = __uint_as_float(e3.y);
      a0 += v0 * bf2f((unsigned short)q0.x) + v1 * bf2f((unsigned short)q1.x) +
            v2 * bf2f((unsigned short)q2.x) + v3 * bf2f((unsigned short)q3.x);
      a1 += v0 * bf2f((unsigned short)(q0.x >> 16)) + v1 * bf2f((unsigned short)(q1.x >> 16)) +
            v2 * bf2f((unsigned short)(q2.x >> 16)) + v3 * bf2f((unsigned short)(q3.x >> 16));
      a2 += v0 * bf2f((unsigned short)q0.y) + v1 * bf2f((unsigned short)q1.y) +
            v2 * bf2f((unsigned short)q2.y) + v3 * bf2f((unsigned short)q3.y);
      a3 += v0 * bf2f((unsigned short)(q0.y >> 16)) + v1 * bf2f((unsigned short)(q1.y >> 16)) +
            v2 * bf2f((unsigned short)(q2.y >> 16)) + v3 * bf2f((unsigned short)(q3.y >> 16));
    }
    for (; j < en; j += 2) {
      uint2 e0 = se[j];
      uint2 q0 = xb2[(size_t)e0.x * 32 + l32];
      float v0 = __uint_as_float(e0.y);
      a0 += v0 * bf2f((unsigned short)q0.x);
      a1 += v0 * bf2f((unsigned short)(q0.x >> 16));
      a2 += v0 * bf2f((unsigned short)q0.y);
      a3 += v0 * bf2f((unsigned short)(q0.y >> 16));
    }
    // merge the two half-wave partials
    a0 += __shfl_xor(a0, 32, 64);
    a1 += __shfl_xor(a1, 32, 64);
    a2 += __shfl_xor(a2, 32, 64);
    a3 += __shfl_xor(a3, 32, 64);
    // + x self
    uint2 xs = xb2[(size_t)gr * 32 + l32];
    a0 += bf2f((unsigned short)xs.x);
    a1 += bf2f((unsigned short)(xs.x >> 16));
    a2 += bf2f((unsigned short)xs.y);
    a3 += bf2f((unsigned short)(xs.y >> 16));
    if (half == 0) {
      uint2 o;
      o.x = (uint)f2bf(a0) | ((uint)f2bf(a1) << 16);
      o.y = (uint)f2bf(a2) | ((uint)f2bf(a3) << 16);
      *reinterpret_cast<uint2*>(&hb[rr * 136 + 4 * l32]) = o;
    }
  }
  __syncthreads();   // hb ready; se dead from here on

  // ---- stage 1: hs = relu(hb @ W1 + b1); wave w = n-tiles w*4..w*4+3 ------
  f32x4 acc[2][4];
#pragma unroll
  for (int a = 0; a < 2; ++a)
#pragma unroll
    for (int b = 0; b < 4; ++b)
#pragma unroll
      for (int c = 0; c < 4; ++c) acc[a][b][c] = 0.f;

  for (int s = 0; s < 4; ++s) {
    bf16x8 af[2];
#pragma unroll
    for (int mr = 0; mr < 2; ++mr) {
      const unsigned short* p = &hb[(mr * 16 + r16) * 136 + s * 32 + g * 4];
      s16x4 lo4 = *reinterpret_cast<const s16x4*>(p);
      s16x4 hi4 = *reinterpret_cast<const s16x4*>(p + 16);
#pragma unroll
      for (int j = 0; j < 4; ++j) { af[mr][j] = lo4[j]; af[mr][4 + j] = hi4[j]; }
    }
#pragma unroll
    for (int nr = 0; nr < 4; ++nr) {
      int t = w * 4 + nr;
      bf16x8 bf = *reinterpret_cast<const bf16x8*>(B1p + (size_t)((t * 4 + s) * 64 + lane) * 8);
      acc[0][nr] = __builtin_amdgcn_mfma_f32_16x16x32_bf16(af[0], bf, acc[0][nr], 0, 0, 0);
      acc[1][nr] = __builtin_amdgcn_mfma_f32_16x16x32_bf16(af[1], bf, acc[1][nr], 0, 0, 0);
    }
  }
  __syncthreads();   // all hb reads done; hs may now overwrite se+hb
#pragma unroll
  for (int mr = 0; mr < 2; ++mr)
#pragma unroll
    for (int nr = 0; nr < 4; ++nr) {
      int nn = w * 64 + nr * 16 + r16;
      float bias = (nn < DH) ? b1[nn] : 0.f;
#pragma unroll
      for (int i = 0; i < 4; ++i) {
        int rl = mr * 16 + g * 4 + i;
        float v = acc[mr][nr][i] + bias;
        v = v > 0.f ? v : 0.f;
        if (nn >= DH) v = 0.f;
        hs[rl * 260 + nn] = f2bf(v);
      }
    }
  __syncthreads();

  // ---- stage 2: out = hs @ W2 + b2; wave w = n-tile w, m-tiles 0..1 -------
  f32x4 acc2[2];
#pragma unroll
  for (int b = 0; b < 2; ++b)
#pragma unroll
    for (int c = 0; c < 4; ++c) acc2[b][c] = 0.f;

  for (int s = 0; s < 8; ++s) {
#pragma unroll
    for (int mt = 0; mt < 2; ++mt) {
      const unsigned short* p = &hs[(mt * 16 + r16) * 260 + s * 32 + g * 4];
      s16x4 lo4 = *reinterpret_cast<const s16x4*>(p);
      s16x4 hi4 = *reinterpret_cast<const s16x4*>(p + 16);
      bf16x8 af;
#pragma unroll
      for (int j = 0; j < 4; ++j) { af[j] = lo4[j]; af[4 + j] = hi4[j]; }
      bf16x8 bf = *reinterpret_cast<const bf16x8*>(B2p + (size_t)((w * 8 + s) * 64 + lane) * 8);
      acc2[mt] = __builtin_amdgcn_mfma_f32_16x16x32_bf16(af, bf, acc2[mt], 0, 0, 0);
    }
  }
#pragma unroll
  for (int mt = 0; mt < 2; ++mt) {
    int nn = w * 16 + r16;
    float bias = b2[nn];
#pragma unroll
    for (int i = 0; i < 4; ++i) {
      int grow = r0 + mt * 16 + g * 4 + i;
      if (grow < NN) out[(size_t)grow * DO + nn] = acc2[mt][i] + bias;
    }
  }
}

extern "C" void kernel_launch(void* const* d_in, const int* in_sizes, int n_in,
                              void* d_out, int out_size, void* d_ws, size_t ws_size,
                              hipStream_t stream) {
  const float* x = (const float*)d_in[0];
  const int* erow = (const int*)d_in[1];
  const int* ecol = (const int*)d_in[2];
  const float* eval_ = (const float*)d_in[3];
  const float* W1 = (const float*)d_in[4];
  const float* b1 = (const float*)d_in[5];
  const float* W2 = (const float*)d_in[6];
  const float* b2 = (const float*)d_in[7];
  float* out = (float*)d_out;

  char* ws = (char*)d_ws;
  size_t o = 0;
  uint* xb = (uint*)(ws + o);          o += (size_t)NN * 64 * 4;   // x bf16, 12.8 MB
  unsigned short* B1p = (unsigned short*)(ws + o); o += 32768 * 2; // 64 KB
  unsigned short* B2p = (unsigned short*)(ws + o); o += 16384 * 2; // 32 KB
  o = (o + 255) & ~(size_t)255;
  int* cnt = (int*)(ws + o);           o += (NBUCK * 4 + 255) & ~(size_t)255;
  int* hist = (int*)(ws + o);          o += (size_t)NBLK_E * NBUCK * 4;  // 1.23 MB
  o = (o + 255) & ~(size_t)255;
  uint2* ep = (uint2*)(ws + o);        // NBUCK*CAP*8 = 12.8 MB

  k_prep<<<CVT_B + NBLK_E + PACK_B, 256, 0, stream>>>(x, xb, erow, hist, W1, W2, B1p, B2p);
  k_scanB<<<NBUCK, 256, 0, stream>>>(hist, cnt);
  k_scatC<<<NBLK_E, 256, 0, stream>>>(erow, ecol, eval_, hist, ep);
  k_spmm_mlp<<<NBUCK, 256, 0, stream>>>(xb, ep, cnt, B1p, b1, B2p, b2, out);
}